// Round 5
// baseline (414.868 us; speedup 1.0000x reference)
//
#include <hip/hip_runtime.h>
#include <hip/hip_bf16.h>

#define HD 64
#define ED 16
#define NU 100000
#define NI 200000
#define NN 300000
#define NE 1250000
#define NP 14

#define RB 512                         // rows per bucket (9 bits)
#define NBKT ((NN + RB - 1) / RB)      // 586 buckets
#define NR8 (NBKT * RB)                // 300032 perm slots (tail = -1)
#define A_ITEMS 16
#define A_CHUNK (256 * A_ITEMS)        // 4096 edges per binning block
#define A_BLOCKS ((NE + A_CHUNK - 1) / A_CHUNK)   // 306
#define DBINS 64                       // degree-sort bins (deg clamped at 63)

typedef __hip_bfloat16 bf16;
typedef unsigned short ushort8v __attribute__((ext_vector_type(8)));

__device__ __forceinline__ float bf2f(unsigned short u) {
    union { unsigned int i; float f; } c; c.i = ((unsigned int)u) << 16; return c.f;
}
__device__ __forceinline__ unsigned short f2b(float x) {
    bf16 h = __float2bfloat16(x);
    unsigned short u; __builtin_memcpy(&u, &h, 2); return u;
}

// ---------------------------------------------------------------------------
// LayerNorm of input embeddings, 8-lane group per row (lane = 8 dims).
// Also converts eigs -> bf16 eb (2 elems/lane, packed 4-B store).
// ---------------------------------------------------------------------------
__global__ void ln_kernel(const float* __restrict__ user_emb,
                          const float* __restrict__ item_emb,
                          const float* __restrict__ eigs,
                          bf16* __restrict__ yb,
                          bf16* __restrict__ eb)
{
    const int tid = blockIdx.x * blockDim.x + threadIdx.x;
    const int r   = tid >> 3;
    const int sub = tid & 7;
    if (r >= NN) return;
    const float* src = (r < NU) ? user_emb + (size_t)r * HD
                                : item_emb + (size_t)(r - NU) * HD;
    const float4 lo = *reinterpret_cast<const float4*>(src + sub * 8);
    const float4 hi = *reinterpret_cast<const float4*>(src + sub * 8 + 4);
    float x[8] = {lo.x, lo.y, lo.z, lo.w, hi.x, hi.y, hi.z, hi.w};

    float sm = 0.0f, sq = 0.0f;
#pragma unroll
    for (int j = 0; j < 8; ++j) { sm += x[j]; sq += x[j] * x[j]; }
    sm += __shfl_xor(sm, 1, 64); sq += __shfl_xor(sq, 1, 64);
    sm += __shfl_xor(sm, 2, 64); sq += __shfl_xor(sq, 2, 64);
    sm += __shfl_xor(sm, 4, 64); sq += __shfl_xor(sq, 4, 64);
    const float mu  = sm * (1.0f / 64.0f);
    const float var = sq * (1.0f / 64.0f) - mu * mu;
    const float inv = rsqrtf(var + 1e-5f);

    ushort8v w;
#pragma unroll
    for (int j = 0; j < 8; ++j) w[j] = f2b((x[j] - mu) * inv);
    *reinterpret_cast<ushort8v*>(yb + (size_t)r * HD + sub * 8) = w;

    // bf16 eig table: 2 elems/lane, one packed 4-B store
    const float2 ev = *reinterpret_cast<const float2*>(eigs + (size_t)r * ED + sub * 2);
    const unsigned int packed = (unsigned int)f2b(ev.x) | ((unsigned int)f2b(ev.y) << 16);
    *reinterpret_cast<unsigned int*>(eb + (size_t)r * ED + sub * 2) = packed;
}

// ------------------- CSR build, stage A1: bucket histogram ------------------
__global__ void bkt_count_kernel(const int* __restrict__ row,
                                 int* __restrict__ bkt_cnt)
{
    __shared__ int hist[NBKT];
    const int tid = threadIdx.x;
    for (int j = tid; j < NBKT; j += 256) hist[j] = 0;
    __syncthreads();
    const int base = blockIdx.x * A_CHUNK;
#pragma unroll
    for (int i = 0; i < A_ITEMS; ++i) {
        const int idx = base + i * 256 + tid;
        if (idx < NE) atomicAdd(&hist[row[idx] >> 9], 1);
    }
    __syncthreads();
    for (int j = tid; j < NBKT; j += 256) {
        const int h = hist[j];
        if (h) atomicAdd(&bkt_cnt[j], h);
    }
}

// ------------- stage A2: exclusive scan of bucket counts (1 blk) -----------
__global__ void bkt_scan_kernel(const int* __restrict__ bkt_cnt,
                                int* __restrict__ bkt_base,
                                int* __restrict__ wq_bkt)
{
    __shared__ int s[1024];
    const int t = threadIdx.x;
    const int v = (t < NBKT) ? bkt_cnt[t] : 0;
    s[t] = v;
    __syncthreads();
    for (int off = 1; off < 1024; off <<= 1) {
        int x = (t >= off) ? s[t - off] : 0;
        __syncthreads();
        s[t] += x;
        __syncthreads();
    }
    if (t < NBKT) {
        const int excl = s[t] - v;
        bkt_base[t] = excl;
        wq_bkt[t]   = excl;
        if (t == NBKT - 1) bkt_base[NBKT] = s[t];   // == NE
    }
}

// --------- stage A3: bin edges into buckets (packed 4-B pairs) -------------
__global__ void bkt_scatter_kernel(const int* __restrict__ row,
                                   const int* __restrict__ col,
                                   const int* __restrict__ pt,
                                   int* __restrict__ wq_bkt,
                                   int* __restrict__ pairs)
{
    __shared__ int hist[NBKT];
    __shared__ int rbase[NBKT];
    __shared__ int roff[NBKT];
    const int tid = threadIdx.x;
    for (int j = tid; j < NBKT; j += 256) { hist[j] = 0; roff[j] = 0; }
    __syncthreads();

    const int base = blockIdx.x * A_CHUNK;
#pragma unroll
    for (int i = 0; i < A_ITEMS; ++i) {
        const int idx = base + i * 256 + tid;
        if (idx < NE) atomicAdd(&hist[row[idx] >> 9], 1);
    }
    __syncthreads();
    for (int j = tid; j < NBKT; j += 256) {
        const int h = hist[j];
        if (h) rbase[j] = atomicAdd(&wq_bkt[j], h);
    }
    __syncthreads();
#pragma unroll
    for (int i = 0; i < A_ITEMS; ++i) {
        const int idx = base + i * 256 + tid;
        if (idx < NE) {
            const int r = row[idx];
            const int b = r >> 9;
            const int v = col[idx] | (pt[idx] << 19) | ((r & (RB - 1)) << 23);
            const int o = atomicAdd(&roff[b], 1);
            pairs[rbase[b] + o] = v;
        }
    }
}

// --------- stage B: per-bucket sort by row + eig-dot precompute ------------
// One block per bucket. Also emits a within-bucket degree-sorted row
// permutation (rowperm) so each 8-row attention wave carries near-equal
// degree. Invalid tail slots get -1.
__global__ void bkt_sort_kernel(const int* __restrict__ bkt_base,
                                const int* __restrict__ pairs,
                                const float* __restrict__ eigs,
                                const bf16* __restrict__ eb,
                                int* __restrict__ rowptr,
                                int* __restrict__ cnt,
                                int2* __restrict__ epacked,
                                int* __restrict__ rowperm)
{
    __shared__ int rcnt[RB], lrp[RB], wq2[RB], ssum[256];
    __shared__ int dhist[DBINS], dbase[DBINS];
    __shared__ float estage[RB * ED];
    const int tid = threadIdx.x;
    const int b   = blockIdx.x;
    const int r0  = b * RB;
    const int s   = bkt_base[b];
    const int e   = bkt_base[b + 1];

    for (int j = tid; j < RB; j += 256) { rcnt[j] = 0; wq2[j] = 0; rowperm[r0 + j] = -1; }
    for (int j = tid; j < DBINS; j += 256) dhist[j] = 0;
    for (int k = tid; k < RB * ED; k += 256) {
        const int g = r0 * ED + k;
        estage[k] = (g < NN * ED) ? eigs[g] : 0.0f;
    }
    __syncthreads();

    for (int i = s + tid; i < e; i += 256)
        atomicAdd(&rcnt[(pairs[i] >> 23) & (RB - 1)], 1);
    __syncthreads();

    const int a0 = rcnt[2 * tid], a1 = rcnt[2 * tid + 1];
    ssum[tid] = a0 + a1;
    __syncthreads();
    for (int off = 1; off < 256; off <<= 1) {
        int x = (tid >= off) ? ssum[tid - off] : 0;
        __syncthreads();
        ssum[tid] += x;
        __syncthreads();
    }
    const int excl = ssum[tid] - (a0 + a1);
    lrp[2 * tid]     = excl;
    lrp[2 * tid + 1] = excl + a0;
    {
        const int r = r0 + 2 * tid;
        if (r < NN)     { rowptr[r]     = s + excl;      cnt[r]     = a0; }
        if (r + 1 < NN) { rowptr[r + 1] = s + excl + a0; cnt[r + 1] = a1; }
    }
    __syncthreads();

    // ---- within-bucket counting sort by degree -> rowperm ----
    const int ra   = r0 + 2 * tid;
    const int bin0 = (a0 < DBINS - 1) ? a0 : (DBINS - 1);
    const int bin1 = (a1 < DBINS - 1) ? a1 : (DBINS - 1);
    if (ra < NN)     atomicAdd(&dhist[bin0], 1);
    if (ra + 1 < NN) atomicAdd(&dhist[bin1], 1);
    __syncthreads();
    ssum[tid] = (tid < DBINS) ? dhist[tid] : 0;
    __syncthreads();
    for (int off = 1; off < DBINS; off <<= 1) {
        int x = (tid >= off) ? ssum[tid - off] : 0;
        __syncthreads();
        ssum[tid] += x;
        __syncthreads();
    }
    if (tid < DBINS) { dbase[tid] = ssum[tid] - dhist[tid]; dhist[tid] = 0; }
    __syncthreads();
    if (ra < NN)     rowperm[r0 + dbase[bin0] + atomicAdd(&dhist[bin0], 1)] = ra;
    if (ra + 1 < NN) rowperm[r0 + dbase[bin1] + atomicAdd(&dhist[bin1], 1)] = ra + 1;
    __syncthreads();   // defensive: separate perm phase from epacked scatter

    for (int i = s + tid; i < e; i += 256) {
        const int v  = pairs[i];
        const int rl = (v >> 23) & (RB - 1);
        const int c  = v & 0x7FFFF;
        const ushort8v* ep = reinterpret_cast<const ushort8v*>(eb + (size_t)c * ED);
        const ushort8v q0 = ep[0], q1 = ep[1];
        const float* er = estage + rl * ED;
        float d = 0.0f;
#pragma unroll
        for (int j = 0; j < 8; ++j) d += bf2f(q0[j]) * er[j];
#pragma unroll
        for (int j = 0; j < 8; ++j) d += bf2f(q1[j]) * er[j + 8];
        const int o   = atomicAdd(&wq2[rl], 1);
        const int pos = s + lrp[rl] + o;
        epacked[pos] = make_int2(v & 0x7FFFFF, __float_as_int(d));
    }
}

// ---------------------------------------------------------------------------
// Fused attention, single sweep, 8-lane group per row (exclusive owner).
// Rows walked through rowperm (degree-sorted within bucket). Edge loop is
// batched by 8 with a sched_barrier(0) fence pinning ALL 8 yb gathers in
// flight before any consume (R4 counters: VGPR=60 proved the compiler had
// re-serialized the batch; the fence forces ~8x memory-level parallelism).
//   out = 0.5*(sum e0*y[c])/d0 + 0.5*(sum e1*y[c])/d1
// LAYER 0 epilogue: in-register LayerNorm(out1) -> yb_next; io=(emb0+out1)/3.
// LAYER 1 epilogue: io += out2/3 -> final mean in d_out.
// ---------------------------------------------------------------------------
template <int LAYER>
__global__ __launch_bounds__(256, 4)   // allow up to 128 VGPR (4 waves/EU)
void attn_row_kernel(const bf16* __restrict__ yb,
                     const int* __restrict__ rowptr,
                     const int* __restrict__ cnt,
                     const int2* __restrict__ epacked,
                     const int* __restrict__ rowperm,
                     const float* __restrict__ lambda0,
                     const float* __restrict__ pemb,
                     const float* __restrict__ user_emb,
                     const float* __restrict__ item_emb,
                     bf16* __restrict__ yb_next,
                     float* __restrict__ io)
{
    __shared__ float e1tab[NP];
    if (threadIdx.x < NP)
        e1tab[threadIdx.x] = __expf(pemb[LAYER * NP + threadIdx.x]);
    __syncthreads();

    const int tid  = blockIdx.x * blockDim.x + threadIdx.x;
    const int g    = tid >> 3;
    const int sub  = tid & 7;
    const int lane = (int)(threadIdx.x & 63);
    const int r    = rowperm[g];
    if (r < 0) return;                    // tail slots (32 of 300032)
    const int deg = cnt[r];
    if (LAYER == 1 && deg == 0) return;   // out2 row = 0: io unchanged

    const int start = rowptr[r];
    const float lam = __expf(lambda0[LAYER]);

    float yrf[8];
    {
        ushort8v u = *reinterpret_cast<const ushort8v*>(yb + (size_t)r * HD + sub * 8);
#pragma unroll
        for (int j = 0; j < 8; ++j) yrf[j] = bf2f(u[j]);
    }

    float U0[8], U1[8];
#pragma unroll
    for (int j = 0; j < 8; ++j) { U0[j] = 0.0f; U1[j] = 0.0f; }
    float d0 = 0.0f, d1 = 0.0f;

    // deg is uniform across the 8-lane group, so all lanes of a group take
    // identical trip counts and every shfl below stays within the group.
    int2 myv = (sub < deg) ? epacked[start + sub] : make_int2(0, 0);
    for (int k0 = 0; k0 < deg; k0 += 8) {
        // prefetch next epacked batch under this batch's compute
        const bool more = (k0 + 8) < deg;
        int2 nxt = make_int2(0, 0);
        if (more && (k0 + 8 + sub) < deg) nxt = epacked[start + k0 + 8 + sub];

        // broadcast the batch's (v, edot) to all lanes of the group
        int   vv[8];
        float ee[8];
#pragma unroll
        for (int kk = 0; kk < 8; ++kk) {
            const int src = (lane & ~7) + kk;
            vv[kk] = __shfl(myv.x, src, 64);
            ee[kk] = __int_as_float(__shfl(myv.y, src, 64));
        }

        const int nb = ((deg - k0) < 8) ? (deg - k0) : 8;

        // issue ALL 8 gathers unconditionally (kk >= nb has vv=0 -> row 0,
        // cache-hot and harmless) so the load cluster is branch-free ...
        ushort8v uc[8];
#pragma unroll
        for (int kk = 0; kk < 8; ++kk)
            uc[kk] = *reinterpret_cast<const ushort8v*>(
                yb + (size_t)(vv[kk] & 0x7FFFF) * HD + sub * 8);
        // ... and pin them in flight: nothing may cross this fence, so the
        // compiler cannot sink loads into the consume phase (R4: VGPR=60
        // showed it had serialized them to save registers).
        __builtin_amdgcn_sched_barrier(0);

        // consume
#pragma unroll
        for (int kk = 0; kk < 8; ++kk) {
            if (kk < nb) {
                float yc[8];
                float sdot = 0.0f;
#pragma unroll
                for (int j = 0; j < 8; ++j) { yc[j] = bf2f(uc[kk][j]); sdot += yrf[j] * yc[j]; }
                sdot += __shfl_xor(sdot, 1, 64);
                sdot += __shfl_xor(sdot, 2, 64);
                sdot += __shfl_xor(sdot, 4, 64);

                const float e0 = __expf(sdot * 0.125f + lam * ee[kk]);
                const float e1 = e1tab[(vv[kk] >> 19) & 15];
                d0 += e0; d1 += e1;
#pragma unroll
                for (int j = 0; j < 8; ++j) {
                    U0[j] += e0 * yc[j];
                    U1[j] += e1 * yc[j];
                }
            }
        }
        myv = nxt;
    }

    const float i0 = deg ? 0.5f / d0 : 0.0f;
    const float i1 = deg ? 0.5f / d1 : 0.0f;
    float acc[8];
#pragma unroll
    for (int j = 0; j < 8; ++j) acc[j] = i0 * U0[j] + i1 * U1[j];

    float* iorow = io + (size_t)r * HD + sub * 8;
    if (LAYER == 0) {
        float sm = 0.0f, sq = 0.0f;
#pragma unroll
        for (int j = 0; j < 8; ++j) { sm += acc[j]; sq += acc[j] * acc[j]; }
        sm += __shfl_xor(sm, 1, 64); sq += __shfl_xor(sq, 1, 64);
        sm += __shfl_xor(sm, 2, 64); sq += __shfl_xor(sq, 2, 64);
        sm += __shfl_xor(sm, 4, 64); sq += __shfl_xor(sq, 4, 64);
        const float mu  = sm * (1.0f / 64.0f);
        const float var = sq * (1.0f / 64.0f) - mu * mu;
        const float inv = rsqrtf(var + 1e-5f);
        ushort8v w;
#pragma unroll
        for (int j = 0; j < 8; ++j) w[j] = f2b((acc[j] - mu) * inv);
        *reinterpret_cast<ushort8v*>(yb_next + (size_t)r * HD + sub * 8) = w;

        const float* e0p = (r < NU) ? user_emb + (size_t)r * HD + sub * 8
                                    : item_emb + (size_t)(r - NU) * HD + sub * 8;
        const float4 lo = *reinterpret_cast<const float4*>(e0p);
        const float4 hi = *reinterpret_cast<const float4*>(e0p + 4);
        const float third = 1.0f / 3.0f;
        *reinterpret_cast<float4*>(iorow) =
            make_float4((lo.x + acc[0]) * third, (lo.y + acc[1]) * third,
                        (lo.z + acc[2]) * third, (lo.w + acc[3]) * third);
        *reinterpret_cast<float4*>(iorow + 4) =
            make_float4((hi.x + acc[4]) * third, (hi.y + acc[5]) * third,
                        (hi.z + acc[6]) * third, (hi.w + acc[7]) * third);
    } else {
        const float third = 1.0f / 3.0f;
        float4 lo = *reinterpret_cast<const float4*>(iorow);
        float4 hi = *reinterpret_cast<const float4*>(iorow + 4);
        lo.x += acc[0] * third; lo.y += acc[1] * third;
        lo.z += acc[2] * third; lo.w += acc[3] * third;
        hi.x += acc[4] * third; hi.y += acc[5] * third;
        hi.z += acc[6] * third; hi.w += acc[7] * third;
        *reinterpret_cast<float4*>(iorow)     = lo;
        *reinterpret_cast<float4*>(iorow + 4) = hi;
    }
}

extern "C" void kernel_launch(void* const* d_in, const int* in_sizes, int n_in,
                              void* d_out, int out_size, void* d_ws, size_t ws_size,
                              hipStream_t stream)
{
    const float* user_emb = (const float*)d_in[0];
    const float* item_emb = (const float*)d_in[1];
    const float* eigs     = (const float*)d_in[2];
    const float* lambda0  = (const float*)d_in[3];
    const float* pemb     = (const float*)d_in[4];
    const int*   indices  = (const int*)d_in[5];
    const int*   ptype    = (const int*)d_in[6];
    const int*   row = indices;
    const int*   col = indices + NE;

    float* io = (float*)d_out;                        // NN*HD fp32 accumulator
    char*  ws = (char*)d_ws;
    bf16* yb       = (bf16*)ws;                       // 38.4 MB
    bf16* yb2      = yb + (size_t)NN * HD;            // 38.4 MB
    bf16* eb       = yb2 + (size_t)NN * HD;           //  9.6 MB
    int*  pairs    = (int*)(eb + (size_t)NN * ED);    // NE      (5 MB)
    int2* epacked  = (int2*)(pairs + NE);             // NE int2 (10 MB)
    int*  rowptr   = (int*)(epacked + NE);            // NN
    int*  cnt      = rowptr + NN;                     // NN
    int*  bkt_cnt  = cnt + NN;                        // NBKT
    int*  bkt_base = bkt_cnt + NBKT;                  // NBKT+1
    int*  wq_bkt   = bkt_base + NBKT + 1;             // NBKT
    int*  rowperm  = wq_bkt + NBKT;                   // NR8 (1.2 MB)
    // total ws ~ 105 MB

    const dim3 blk(256);
    const int grid8 = (NR8 * 8) / 256;                // 8-lane group per perm slot

    // ---- LayerNorm + bf16 eig table (eb consumed by bkt_sort) ----
    ln_kernel<<<(NN * 8 + 255) / 256, blk, 0, stream>>>(user_emb, item_emb, eigs, yb, eb);

    // ---- CSR build: two-level binned counting sort + degree perm ----
    hipMemsetAsync(bkt_cnt, 0, NBKT * sizeof(int), stream);
    bkt_count_kernel<<<A_BLOCKS, blk, 0, stream>>>(row, bkt_cnt);
    bkt_scan_kernel<<<1, 1024, 0, stream>>>(bkt_cnt, bkt_base, wq_bkt);
    bkt_scatter_kernel<<<A_BLOCKS, blk, 0, stream>>>(row, col, ptype, wq_bkt, pairs);
    bkt_sort_kernel<<<NBKT, blk, 0, stream>>>(bkt_base, pairs, eigs, eb,
                                              rowptr, cnt, epacked, rowperm);

    // ---- layer 0 (attn fuses ln2 + final-mean prep) ----
    attn_row_kernel<0><<<grid8, blk, 0, stream>>>(yb, rowptr, cnt, epacked, rowperm,
                                                  lambda0, pemb, user_emb,
                                                  item_emb, yb2, io);
    // ---- layer 1 (adds out2/3 -> final mean in d_out) ----
    attn_row_kernel<1><<<grid8, blk, 0, stream>>>(yb2, rowptr, cnt, epacked, rowperm,
                                                  lambda0, pemb, user_emb,
                                                  item_emb, nullptr, io);
}

// Round 7
// 405.900 us; speedup vs baseline: 1.0221x; 1.0221x over previous
//
#include <hip/hip_runtime.h>
#include <hip/hip_bf16.h>

#define HD 64
#define ED 16
#define NU 100000
#define NI 200000
#define NN 300000
#define NE 1250000
#define NP 14

#define RB 512                         // rows per bucket (9 bits)
#define NBKT ((NN + RB - 1) / RB)      // 586 buckets
#define NR8 (NBKT * RB)                // 300032 perm slots (tail invalid)
#define A_ITEMS 16
#define A_CHUNK (256 * A_ITEMS)        // 4096 edges per binning block
#define A_BLOCKS ((NE + A_CHUNK - 1) / A_CHUNK)   // 306
#define DBINS 64                       // degree-sort bins (bin clamped at 63)

typedef __hip_bfloat16 bf16;
typedef unsigned short ushort8v __attribute__((ext_vector_type(8)));

__device__ __forceinline__ float bf2f(unsigned short u) {
    union { unsigned int i; float f; } c; c.i = ((unsigned int)u) << 16; return c.f;
}
__device__ __forceinline__ unsigned short f2b(float x) {
    bf16 h = __float2bfloat16(x);
    unsigned short u; __builtin_memcpy(&u, &h, 2); return u;
}

// ---------------------------------------------------------------------------
// LayerNorm of input embeddings, 8-lane group per row (lane = 8 dims).
// Also converts eigs -> bf16 eb (2 elems/lane, packed 4-B store).
// ---------------------------------------------------------------------------
__global__ void ln_kernel(const float* __restrict__ user_emb,
                          const float* __restrict__ item_emb,
                          const float* __restrict__ eigs,
                          bf16* __restrict__ yb,
                          bf16* __restrict__ eb)
{
    const int tid = blockIdx.x * blockDim.x + threadIdx.x;
    const int r   = tid >> 3;
    const int sub = tid & 7;
    if (r >= NN) return;
    const float* src = (r < NU) ? user_emb + (size_t)r * HD
                                : item_emb + (size_t)(r - NU) * HD;
    const float4 lo = *reinterpret_cast<const float4*>(src + sub * 8);
    const float4 hi = *reinterpret_cast<const float4*>(src + sub * 8 + 4);
    float x[8] = {lo.x, lo.y, lo.z, lo.w, hi.x, hi.y, hi.z, hi.w};

    float sm = 0.0f, sq = 0.0f;
#pragma unroll
    for (int j = 0; j < 8; ++j) { sm += x[j]; sq += x[j] * x[j]; }
    sm += __shfl_xor(sm, 1, 64); sq += __shfl_xor(sq, 1, 64);
    sm += __shfl_xor(sm, 2, 64); sq += __shfl_xor(sq, 2, 64);
    sm += __shfl_xor(sm, 4, 64); sq += __shfl_xor(sq, 4, 64);
    const float mu  = sm * (1.0f / 64.0f);
    const float var = sq * (1.0f / 64.0f) - mu * mu;
    const float inv = rsqrtf(var + 1e-5f);

    ushort8v w;
#pragma unroll
    for (int j = 0; j < 8; ++j) w[j] = f2b((x[j] - mu) * inv);
    *reinterpret_cast<ushort8v*>(yb + (size_t)r * HD + sub * 8) = w;

    // bf16 eig table: 2 elems/lane, one packed 4-B store
    const float2 ev = *reinterpret_cast<const float2*>(eigs + (size_t)r * ED + sub * 2);
    const unsigned int packed = (unsigned int)f2b(ev.x) | ((unsigned int)f2b(ev.y) << 16);
    *reinterpret_cast<unsigned int*>(eb + (size_t)r * ED + sub * 2) = packed;
}

// ------------------- CSR build, stage A1: bucket histogram ------------------
__global__ void bkt_count_kernel(const int* __restrict__ row,
                                 int* __restrict__ bkt_cnt)
{
    __shared__ int hist[NBKT];
    const int tid = threadIdx.x;
    for (int j = tid; j < NBKT; j += 256) hist[j] = 0;
    __syncthreads();
    const int base = blockIdx.x * A_CHUNK;
#pragma unroll
    for (int i = 0; i < A_ITEMS; ++i) {
        const int idx = base + i * 256 + tid;
        if (idx < NE) atomicAdd(&hist[row[idx] >> 9], 1);
    }
    __syncthreads();
    for (int j = tid; j < NBKT; j += 256) {
        const int h = hist[j];
        if (h) atomicAdd(&bkt_cnt[j], h);
    }
}

// ------------- stage A2: exclusive scan of bucket counts (1 blk) -----------
__global__ void bkt_scan_kernel(const int* __restrict__ bkt_cnt,
                                int* __restrict__ bkt_base,
                                int* __restrict__ wq_bkt)
{
    __shared__ int s[1024];
    const int t = threadIdx.x;
    const int v = (t < NBKT) ? bkt_cnt[t] : 0;
    s[t] = v;
    __syncthreads();
    for (int off = 1; off < 1024; off <<= 1) {
        int x = (t >= off) ? s[t - off] : 0;
        __syncthreads();
        s[t] += x;
        __syncthreads();
    }
    if (t < NBKT) {
        const int excl = s[t] - v;
        bkt_base[t] = excl;
        wq_bkt[t]   = excl;
        if (t == NBKT - 1) bkt_base[NBKT] = s[t];   // == NE
    }
}

// --------- stage A3: bin edges into buckets (packed 4-B pairs) -------------
__global__ void bkt_scatter_kernel(const int* __restrict__ row,
                                   const int* __restrict__ col,
                                   const int* __restrict__ pt,
                                   int* __restrict__ wq_bkt,
                                   int* __restrict__ pairs)
{
    __shared__ int hist[NBKT];
    __shared__ int rbase[NBKT];
    __shared__ int roff[NBKT];
    const int tid = threadIdx.x;
    for (int j = tid; j < NBKT; j += 256) { hist[j] = 0; roff[j] = 0; }
    __syncthreads();

    const int base = blockIdx.x * A_CHUNK;
#pragma unroll
    for (int i = 0; i < A_ITEMS; ++i) {
        const int idx = base + i * 256 + tid;
        if (idx < NE) atomicAdd(&hist[row[idx] >> 9], 1);
    }
    __syncthreads();
    for (int j = tid; j < NBKT; j += 256) {
        const int h = hist[j];
        if (h) rbase[j] = atomicAdd(&wq_bkt[j], h);
    }
    __syncthreads();
#pragma unroll
    for (int i = 0; i < A_ITEMS; ++i) {
        const int idx = base + i * 256 + tid;
        if (idx < NE) {
            const int r = row[idx];
            const int b = r >> 9;
            const int v = col[idx] | (pt[idx] << 19) | ((r & (RB - 1)) << 23);
            const int o = atomicAdd(&roff[b], 1);
            pairs[rbase[b] + o] = v;
        }
    }
}

// --------- stage B: per-bucket sort by row + eig-dot precompute ------------
// One block per bucket. Emits degree-sorted perm slots as PACKED rinfo:
//   rinfo[slot] = { rowptr_start, r | deg<<19 }   (invalid slot: y = -1)
// so the attention prologue is ONE coalesced 8-B load instead of
// rowperm -> cnt/rowptr dependent scattered loads.
__global__ void bkt_sort_kernel(const int* __restrict__ bkt_base,
                                const int* __restrict__ pairs,
                                const float* __restrict__ eigs,
                                const bf16* __restrict__ eb,
                                int2* __restrict__ rinfo,
                                int2* __restrict__ epacked)
{
    __shared__ int rcnt[RB], lrp[RB], wq2[RB], ssum[256];
    __shared__ int dhist[DBINS], dbase[DBINS];
    __shared__ int perml[RB];
    __shared__ float estage[RB * ED];
    const int tid = threadIdx.x;
    const int b   = blockIdx.x;
    const int r0  = b * RB;
    const int s   = bkt_base[b];
    const int e   = bkt_base[b + 1];

    for (int j = tid; j < RB; j += 256) { rcnt[j] = 0; wq2[j] = 0; perml[j] = -1; }
    for (int j = tid; j < DBINS; j += 256) dhist[j] = 0;
    for (int k = tid; k < RB * ED; k += 256) {
        const int g = r0 * ED + k;
        estage[k] = (g < NN * ED) ? eigs[g] : 0.0f;
    }
    __syncthreads();

    for (int i = s + tid; i < e; i += 256)
        atomicAdd(&rcnt[(pairs[i] >> 23) & (RB - 1)], 1);
    __syncthreads();

    const int a0 = rcnt[2 * tid], a1 = rcnt[2 * tid + 1];
    ssum[tid] = a0 + a1;
    __syncthreads();
    for (int off = 1; off < 256; off <<= 1) {
        int x = (tid >= off) ? ssum[tid - off] : 0;
        __syncthreads();
        ssum[tid] += x;
        __syncthreads();
    }
    const int excl = ssum[tid] - (a0 + a1);
    lrp[2 * tid]     = excl;
    lrp[2 * tid + 1] = excl + a0;
    __syncthreads();

    // ---- within-bucket counting sort by degree -> perml (LDS) ----
    const int ra   = r0 + 2 * tid;
    const int bin0 = (a0 < DBINS - 1) ? a0 : (DBINS - 1);
    const int bin1 = (a1 < DBINS - 1) ? a1 : (DBINS - 1);
    if (ra < NN)     atomicAdd(&dhist[bin0], 1);
    if (ra + 1 < NN) atomicAdd(&dhist[bin1], 1);
    __syncthreads();
    ssum[tid] = (tid < DBINS) ? dhist[tid] : 0;
    __syncthreads();
    for (int off = 1; off < DBINS; off <<= 1) {
        int x = (tid >= off) ? ssum[tid - off] : 0;
        __syncthreads();
        ssum[tid] += x;
        __syncthreads();
    }
    if (tid < DBINS) { dbase[tid] = ssum[tid] - dhist[tid]; dhist[tid] = 0; }
    __syncthreads();
    if (ra < NN)     perml[dbase[bin0] + atomicAdd(&dhist[bin0], 1)] = 2 * tid;
    if (ra + 1 < NN) perml[dbase[bin1] + atomicAdd(&dhist[bin1], 1)] = 2 * tid + 1;
    __syncthreads();

    // ---- emit packed rinfo per perm slot ----
    for (int j = tid; j < RB; j += 256) {
        const int rl = perml[j];
        int2 out;
        if (rl >= 0) {
            int dg = rcnt[rl]; if (dg > 0xFFF) dg = 0xFFF;
            out = make_int2(s + lrp[rl], (r0 + rl) | (dg << 19));
        } else {
            out = make_int2(0, -1);
        }
        rinfo[r0 + j] = out;
    }

    for (int i = s + tid; i < e; i += 256) {
        const int v  = pairs[i];
        const int rl = (v >> 23) & (RB - 1);
        const int c  = v & 0x7FFFF;
        const ushort8v* ep = reinterpret_cast<const ushort8v*>(eb + (size_t)c * ED);
        const ushort8v q0 = ep[0], q1 = ep[1];
        const float* er = estage + rl * ED;
        float d = 0.0f;
#pragma unroll
        for (int j = 0; j < 8; ++j) d += bf2f(q0[j]) * er[j];
#pragma unroll
        for (int j = 0; j < 8; ++j) d += bf2f(q1[j]) * er[j + 8];
        const int o   = atomicAdd(&wq2[rl], 1);
        const int pos = s + lrp[rl] + o;
        epacked[pos] = make_int2(v & 0x7FFFFF, __float_as_int(d));
    }
}

// ---------------------------------------------------------------------------
// Fused attention, single sweep, 8-lane group per row (exclusive owner).
// Rows walked through degree-sorted rinfo slots. The 8-edge gather batch is
// forced into flight with inline asm: 8 volatile global_load_dwordx4 into
// named registers, then ONE s_waitcnt vmcnt(0) with all 8 results as tied
// "+v" operands -- dataflow the compiler cannot re-serialize (R4/R5: the
// pure-C version was compiled back to load->wait->consume, VGPR=60).
//   out = 0.5*(sum e0*y[c])/d0 + 0.5*(sum e1*y[c])/d1
// LAYER 0 epilogue: in-register LayerNorm(out1) -> yb_next; io=(emb0+out1)/3.
// LAYER 1 epilogue: io += out2/3 -> final mean in d_out.
// ---------------------------------------------------------------------------
template <int LAYER>
__global__ __launch_bounds__(256, 4)   // allow up to 128 VGPR
void attn_row_kernel(const bf16* __restrict__ yb,
                     const int2* __restrict__ rinfo,
                     const int2* __restrict__ epacked,
                     const float* __restrict__ lambda0,
                     const float* __restrict__ pemb,
                     const float* __restrict__ user_emb,
                     const float* __restrict__ item_emb,
                     bf16* __restrict__ yb_next,
                     float* __restrict__ io)
{
    __shared__ float e1tab[NP];
    if (threadIdx.x < NP)
        e1tab[threadIdx.x] = __expf(pemb[LAYER * NP + threadIdx.x]);
    __syncthreads();

    const int tid  = blockIdx.x * blockDim.x + threadIdx.x;
    const int g    = tid >> 3;
    const int sub  = tid & 7;
    const int lane = (int)(threadIdx.x & 63);
    const int2 ri  = rinfo[g];
    if (ri.y < 0) return;                 // tail slots (32 of 300032)
    const int r    = ri.y & 0x7FFFF;
    const int deg  = (ri.y >> 19) & 0xFFF;
    if (LAYER == 1 && deg == 0) return;   // out2 row = 0: io unchanged

    const int start = ri.x;
    const float lam = __expf(lambda0[LAYER]);

    float yrf[8];
    {
        ushort8v u = *reinterpret_cast<const ushort8v*>(yb + (size_t)r * HD + sub * 8);
#pragma unroll
        for (int j = 0; j < 8; ++j) yrf[j] = bf2f(u[j]);
    }

    float U0[8], U1[8];
#pragma unroll
    for (int j = 0; j < 8; ++j) { U0[j] = 0.0f; U1[j] = 0.0f; }
    float d0 = 0.0f, d1 = 0.0f;

    const bf16* ybs = yb + (size_t)sub * 8;   // lane's dim-slice base

    // deg is uniform across the 8-lane group, so all lanes of a group take
    // identical trip counts and every shfl below stays within the group.
    int2 myv = (sub < deg) ? epacked[start + sub] : make_int2(0, 0);
    for (int k0 = 0; k0 < deg; k0 += 8) {
        // prefetch next epacked batch under this batch's compute
        const bool more = (k0 + 8) < deg;
        int2 nxt = make_int2(0, 0);
        if (more && (k0 + 8 + sub) < deg) nxt = epacked[start + k0 + 8 + sub];

        // broadcast the batch's (v, edot) to all lanes of the group
        int   vv[8];
        float ee[8];
#pragma unroll
        for (int kk = 0; kk < 8; ++kk) {
            const int src = (lane & ~7) + kk;
            vv[kk] = __shfl(myv.x, src, 64);
            ee[kk] = __int_as_float(__shfl(myv.y, src, 64));
        }

        const int nb = ((deg - k0) < 8) ? (deg - k0) : 8;

        // ---- forced-MLP gather cluster (kk >= nb reads row 0: harmless) ----
        const bf16* p0 = ybs + (size_t)(vv[0] & 0x7FFFF) * HD;
        const bf16* p1 = ybs + (size_t)(vv[1] & 0x7FFFF) * HD;
        const bf16* p2 = ybs + (size_t)(vv[2] & 0x7FFFF) * HD;
        const bf16* p3 = ybs + (size_t)(vv[3] & 0x7FFFF) * HD;
        const bf16* p4 = ybs + (size_t)(vv[4] & 0x7FFFF) * HD;
        const bf16* p5 = ybs + (size_t)(vv[5] & 0x7FFFF) * HD;
        const bf16* p6 = ybs + (size_t)(vv[6] & 0x7FFFF) * HD;
        const bf16* p7 = ybs + (size_t)(vv[7] & 0x7FFFF) * HD;
        ushort8v u0, u1, u2, u3, u4, u5, u6, u7;
        asm volatile("global_load_dwordx4 %0, %1, off" : "=v"(u0) : "v"(p0));
        asm volatile("global_load_dwordx4 %0, %1, off" : "=v"(u1) : "v"(p1));
        asm volatile("global_load_dwordx4 %0, %1, off" : "=v"(u2) : "v"(p2));
        asm volatile("global_load_dwordx4 %0, %1, off" : "=v"(u3) : "v"(p3));
        asm volatile("global_load_dwordx4 %0, %1, off" : "=v"(u4) : "v"(p4));
        asm volatile("global_load_dwordx4 %0, %1, off" : "=v"(u5) : "v"(p5));
        asm volatile("global_load_dwordx4 %0, %1, off" : "=v"(u6) : "v"(p6));
        asm volatile("global_load_dwordx4 %0, %1, off" : "=v"(u7) : "v"(p7));
        // One wait for the whole batch; tied operands pin all 8 results
        // live across it -- consumes cannot hoist, loads cannot sink.
        asm volatile("s_waitcnt vmcnt(0)"
                     : "+v"(u0), "+v"(u1), "+v"(u2), "+v"(u3),
                       "+v"(u4), "+v"(u5), "+v"(u6), "+v"(u7));

        // ---- consume ----
        auto consume = [&](const ushort8v& uc, int vk, float ek) {
            float yc[8];
            float sdot = 0.0f;
#pragma unroll
            for (int j = 0; j < 8; ++j) { yc[j] = bf2f(uc[j]); sdot += yrf[j] * yc[j]; }
            sdot += __shfl_xor(sdot, 1, 64);
            sdot += __shfl_xor(sdot, 2, 64);
            sdot += __shfl_xor(sdot, 4, 64);
            const float e0 = __expf(sdot * 0.125f + lam * ek);
            const float e1 = e1tab[(vk >> 19) & 15];
            d0 += e0; d1 += e1;
#pragma unroll
            for (int j = 0; j < 8; ++j) {
                U0[j] += e0 * yc[j];
                U1[j] += e1 * yc[j];
            }
        };
        if (nb > 0) consume(u0, vv[0], ee[0]);
        if (nb > 1) consume(u1, vv[1], ee[1]);
        if (nb > 2) consume(u2, vv[2], ee[2]);
        if (nb > 3) consume(u3, vv[3], ee[3]);
        if (nb > 4) consume(u4, vv[4], ee[4]);
        if (nb > 5) consume(u5, vv[5], ee[5]);
        if (nb > 6) consume(u6, vv[6], ee[6]);
        if (nb > 7) consume(u7, vv[7], ee[7]);

        myv = nxt;
    }

    const float i0 = deg ? 0.5f / d0 : 0.0f;
    const float i1 = deg ? 0.5f / d1 : 0.0f;
    float acc[8];
#pragma unroll
    for (int j = 0; j < 8; ++j) acc[j] = i0 * U0[j] + i1 * U1[j];

    float* iorow = io + (size_t)r * HD + sub * 8;
    if (LAYER == 0) {
        float sm = 0.0f, sq = 0.0f;
#pragma unroll
        for (int j = 0; j < 8; ++j) { sm += acc[j]; sq += acc[j] * acc[j]; }
        sm += __shfl_xor(sm, 1, 64); sq += __shfl_xor(sq, 1, 64);
        sm += __shfl_xor(sm, 2, 64); sq += __shfl_xor(sq, 2, 64);
        sm += __shfl_xor(sm, 4, 64); sq += __shfl_xor(sq, 4, 64);
        const float mu  = sm * (1.0f / 64.0f);
        const float var = sq * (1.0f / 64.0f) - mu * mu;
        const float inv = rsqrtf(var + 1e-5f);
        ushort8v w;
#pragma unroll
        for (int j = 0; j < 8; ++j) w[j] = f2b((acc[j] - mu) * inv);
        *reinterpret_cast<ushort8v*>(yb_next + (size_t)r * HD + sub * 8) = w;

        const float* e0p = (r < NU) ? user_emb + (size_t)r * HD + sub * 8
                                    : item_emb + (size_t)(r - NU) * HD + sub * 8;
        const float4 lo = *reinterpret_cast<const float4*>(e0p);
        const float4 hi = *reinterpret_cast<const float4*>(e0p + 4);
        const float third = 1.0f / 3.0f;
        *reinterpret_cast<float4*>(iorow) =
            make_float4((lo.x + acc[0]) * third, (lo.y + acc[1]) * third,
                        (lo.z + acc[2]) * third, (lo.w + acc[3]) * third);
        *reinterpret_cast<float4*>(iorow + 4) =
            make_float4((hi.x + acc[4]) * third, (hi.y + acc[5]) * third,
                        (hi.z + acc[6]) * third, (hi.w + acc[7]) * third);
    } else {
        const float third = 1.0f / 3.0f;
        float4 lo = *reinterpret_cast<const float4*>(iorow);
        float4 hi = *reinterpret_cast<const float4*>(iorow + 4);
        lo.x += acc[0] * third; lo.y += acc[1] * third;
        lo.z += acc[2] * third; lo.w += acc[3] * third;
        hi.x += acc[4] * third; hi.y += acc[5] * third;
        hi.z += acc[6] * third; hi.w += acc[7] * third;
        *reinterpret_cast<float4*>(iorow)     = lo;
        *reinterpret_cast<float4*>(iorow + 4) = hi;
    }
}

extern "C" void kernel_launch(void* const* d_in, const int* in_sizes, int n_in,
                              void* d_out, int out_size, void* d_ws, size_t ws_size,
                              hipStream_t stream)
{
    const float* user_emb = (const float*)d_in[0];
    const float* item_emb = (const float*)d_in[1];
    const float* eigs     = (const float*)d_in[2];
    const float* lambda0  = (const float*)d_in[3];
    const float* pemb     = (const float*)d_in[4];
    const int*   indices  = (const int*)d_in[5];
    const int*   ptype    = (const int*)d_in[6];
    const int*   row = indices;
    const int*   col = indices + NE;

    float* io = (float*)d_out;                        // NN*HD fp32 accumulator
    char*  ws = (char*)d_ws;
    bf16* yb       = (bf16*)ws;                       // 38.4 MB
    bf16* yb2      = yb + (size_t)NN * HD;            // 38.4 MB
    bf16* eb       = yb2 + (size_t)NN * HD;           //  9.6 MB
    int*  pairs    = (int*)(eb + (size_t)NN * ED);    // NE      (5 MB)
    int2* epacked  = (int2*)(pairs + NE);             // NE int2 (10 MB)
    int2* rinfo    = epacked + NE;                    // NR8 int2 (2.4 MB)
    int*  bkt_cnt  = (int*)(rinfo + NR8);             // NBKT
    int*  bkt_base = bkt_cnt + NBKT;                  // NBKT+1
    int*  wq_bkt   = bkt_base + NBKT + 1;             // NBKT
    // total ws ~ 104 MB

    const dim3 blk(256);
    const int grid8 = (NR8 * 8) / 256;                // 8-lane group per perm slot

    // ---- LayerNorm + bf16 eig table (eb consumed by bkt_sort) ----
    ln_kernel<<<(NN * 8 + 255) / 256, blk, 0, stream>>>(user_emb, item_emb, eigs, yb, eb);

    // ---- CSR build: two-level binned counting sort + degree perm ----
    hipMemsetAsync(bkt_cnt, 0, NBKT * sizeof(int), stream);
    bkt_count_kernel<<<A_BLOCKS, blk, 0, stream>>>(row, bkt_cnt);
    bkt_scan_kernel<<<1, 1024, 0, stream>>>(bkt_cnt, bkt_base, wq_bkt);
    bkt_scatter_kernel<<<A_BLOCKS, blk, 0, stream>>>(row, col, ptype, wq_bkt, pairs);
    bkt_sort_kernel<<<NBKT, blk, 0, stream>>>(bkt_base, pairs, eigs, eb,
                                              rinfo, epacked);

    // ---- layer 0 (attn fuses ln2 + final-mean prep) ----
    attn_row_kernel<0><<<grid8, blk, 0, stream>>>(yb, rinfo, epacked,
                                                  lambda0, pemb, user_emb,
                                                  item_emb, yb2, io);
    // ---- layer 1 (adds out2/3 -> final mean in d_out) ----
    attn_row_kernel<1><<<grid8, blk, 0, stream>>>(yb2, rinfo, epacked,
                                                  lambda0, pemb, user_emb,
                                                  item_emb, nullptr, io);
}

// Round 8
// 401.120 us; speedup vs baseline: 1.0343x; 1.0119x over previous
//
#include <hip/hip_runtime.h>
#include <hip/hip_bf16.h>

#define HD 64
#define ED 16
#define NU 100000
#define NI 200000
#define NN 300000
#define NE 1250000
#define NP 14

#define RB 512                         // rows per bucket (9 bits)
#define NBKT ((NN + RB - 1) / RB)      // 586 buckets
#define NR8 (NBKT * RB)                // 300032 perm slots (tail invalid)
#define A_ITEMS 16
#define A_CHUNK (256 * A_ITEMS)        // 4096 edges per binning block
#define A_BLOCKS ((NE + A_CHUNK - 1) / A_CHUNK)   // 306
#define DBINS 64                       // degree-sort bins (bin clamped at 63)
#define IT 4                           // rows per group (pipelined)

typedef __hip_bfloat16 bf16;
typedef unsigned short ushort8v __attribute__((ext_vector_type(8)));
typedef float  float4v __attribute__((ext_vector_type(4)));
typedef int    int2v   __attribute__((ext_vector_type(2)));

__device__ __forceinline__ float bf2f(unsigned short u) {
    union { unsigned int i; float f; } c; c.i = ((unsigned int)u) << 16; return c.f;
}
__device__ __forceinline__ unsigned short f2b(float x) {
    bf16 h = __float2bfloat16(x);
    unsigned short u; __builtin_memcpy(&u, &h, 2); return u;
}

// ---------------------------------------------------------------------------
// LayerNorm of input embeddings, 8-lane group per row (lane = 8 dims).
// Also converts eigs -> bf16 eb (2 elems/lane, packed 4-B store).
// ---------------------------------------------------------------------------
__global__ void ln_kernel(const float* __restrict__ user_emb,
                          const float* __restrict__ item_emb,
                          const float* __restrict__ eigs,
                          bf16* __restrict__ yb,
                          bf16* __restrict__ eb)
{
    const int tid = blockIdx.x * blockDim.x + threadIdx.x;
    const int r   = tid >> 3;
    const int sub = tid & 7;
    if (r >= NN) return;
    const float* src = (r < NU) ? user_emb + (size_t)r * HD
                                : item_emb + (size_t)(r - NU) * HD;
    const float4 lo = *reinterpret_cast<const float4*>(src + sub * 8);
    const float4 hi = *reinterpret_cast<const float4*>(src + sub * 8 + 4);
    float x[8] = {lo.x, lo.y, lo.z, lo.w, hi.x, hi.y, hi.z, hi.w};

    float sm = 0.0f, sq = 0.0f;
#pragma unroll
    for (int j = 0; j < 8; ++j) { sm += x[j]; sq += x[j] * x[j]; }
    sm += __shfl_xor(sm, 1, 64); sq += __shfl_xor(sq, 1, 64);
    sm += __shfl_xor(sm, 2, 64); sq += __shfl_xor(sq, 2, 64);
    sm += __shfl_xor(sm, 4, 64); sq += __shfl_xor(sq, 4, 64);
    const float mu  = sm * (1.0f / 64.0f);
    const float var = sq * (1.0f / 64.0f) - mu * mu;
    const float inv = rsqrtf(var + 1e-5f);

    ushort8v w;
#pragma unroll
    for (int j = 0; j < 8; ++j) w[j] = f2b((x[j] - mu) * inv);
    *reinterpret_cast<ushort8v*>(yb + (size_t)r * HD + sub * 8) = w;

    // bf16 eig table: 2 elems/lane, one packed 4-B store
    const float2 ev = *reinterpret_cast<const float2*>(eigs + (size_t)r * ED + sub * 2);
    const unsigned int packed = (unsigned int)f2b(ev.x) | ((unsigned int)f2b(ev.y) << 16);
    *reinterpret_cast<unsigned int*>(eb + (size_t)r * ED + sub * 2) = packed;
}

// ------------------- CSR build, stage A1: bucket histogram ------------------
__global__ void bkt_count_kernel(const int* __restrict__ row,
                                 int* __restrict__ bkt_cnt)
{
    __shared__ int hist[NBKT];
    const int tid = threadIdx.x;
    for (int j = tid; j < NBKT; j += 256) hist[j] = 0;
    __syncthreads();
    const int base = blockIdx.x * A_CHUNK;
#pragma unroll
    for (int i = 0; i < A_ITEMS; ++i) {
        const int idx = base + i * 256 + tid;
        if (idx < NE) atomicAdd(&hist[row[idx] >> 9], 1);
    }
    __syncthreads();
    for (int j = tid; j < NBKT; j += 256) {
        const int h = hist[j];
        if (h) atomicAdd(&bkt_cnt[j], h);
    }
}

// ------------- stage A2: exclusive scan of bucket counts (1 blk) -----------
__global__ void bkt_scan_kernel(const int* __restrict__ bkt_cnt,
                                int* __restrict__ bkt_base,
                                int* __restrict__ wq_bkt)
{
    __shared__ int s[1024];
    const int t = threadIdx.x;
    const int v = (t < NBKT) ? bkt_cnt[t] : 0;
    s[t] = v;
    __syncthreads();
    for (int off = 1; off < 1024; off <<= 1) {
        int x = (t >= off) ? s[t - off] : 0;
        __syncthreads();
        s[t] += x;
        __syncthreads();
    }
    if (t < NBKT) {
        const int excl = s[t] - v;
        bkt_base[t] = excl;
        wq_bkt[t]   = excl;
        if (t == NBKT - 1) bkt_base[NBKT] = s[t];   // == NE
    }
}

// --------- stage A3: bin edges into buckets (packed 4-B pairs) -------------
__global__ void bkt_scatter_kernel(const int* __restrict__ row,
                                   const int* __restrict__ col,
                                   const int* __restrict__ pt,
                                   int* __restrict__ wq_bkt,
                                   int* __restrict__ pairs)
{
    __shared__ int hist[NBKT];
    __shared__ int rbase[NBKT];
    __shared__ int roff[NBKT];
    const int tid = threadIdx.x;
    for (int j = tid; j < NBKT; j += 256) { hist[j] = 0; roff[j] = 0; }
    __syncthreads();

    const int base = blockIdx.x * A_CHUNK;
#pragma unroll
    for (int i = 0; i < A_ITEMS; ++i) {
        const int idx = base + i * 256 + tid;
        if (idx < NE) atomicAdd(&hist[row[idx] >> 9], 1);
    }
    __syncthreads();
    for (int j = tid; j < NBKT; j += 256) {
        const int h = hist[j];
        if (h) rbase[j] = atomicAdd(&wq_bkt[j], h);
    }
    __syncthreads();
#pragma unroll
    for (int i = 0; i < A_ITEMS; ++i) {
        const int idx = base + i * 256 + tid;
        if (idx < NE) {
            const int r = row[idx];
            const int b = r >> 9;
            const int v = col[idx] | (pt[idx] << 19) | ((r & (RB - 1)) << 23);
            const int o = atomicAdd(&roff[b], 1);
            pairs[rbase[b] + o] = v;
        }
    }
}

// --------- stage B: per-bucket sort by row + eig-dot precompute ------------
// One block per bucket. Emits DESCENDING-degree perm slots as PACKED rinfo:
//   rinfo[slot] = { rowptr_start, r | deg<<19 }   (invalid slot: y = -1)
// Descending order = longest-job-first scheduling for the attention grid
// (heavy multi-batch waves start early, no tail pile-up); invalid slots
// stay at the end of each bucket's 512-slot range.
__global__ void bkt_sort_kernel(const int* __restrict__ bkt_base,
                                const int* __restrict__ pairs,
                                const float* __restrict__ eigs,
                                const bf16* __restrict__ eb,
                                int2* __restrict__ rinfo,
                                int2* __restrict__ epacked)
{
    __shared__ int rcnt[RB], lrp[RB], wq2[RB], ssum[256];
    __shared__ int dhist[DBINS], dbase[DBINS];
    __shared__ int perml[RB];
    __shared__ float estage[RB * ED];
    const int tid = threadIdx.x;
    const int b   = blockIdx.x;
    const int r0  = b * RB;
    const int s   = bkt_base[b];
    const int e   = bkt_base[b + 1];

    for (int j = tid; j < RB; j += 256) { rcnt[j] = 0; wq2[j] = 0; perml[j] = -1; }
    for (int j = tid; j < DBINS; j += 256) dhist[j] = 0;
    for (int k = tid; k < RB * ED; k += 256) {
        const int g = r0 * ED + k;
        estage[k] = (g < NN * ED) ? eigs[g] : 0.0f;
    }
    __syncthreads();

    for (int i = s + tid; i < e; i += 256)
        atomicAdd(&rcnt[(pairs[i] >> 23) & (RB - 1)], 1);
    __syncthreads();

    const int a0 = rcnt[2 * tid], a1 = rcnt[2 * tid + 1];
    ssum[tid] = a0 + a1;
    __syncthreads();
    for (int off = 1; off < 256; off <<= 1) {
        int x = (tid >= off) ? ssum[tid - off] : 0;
        __syncthreads();
        ssum[tid] += x;
        __syncthreads();
    }
    const int excl = ssum[tid] - (a0 + a1);
    lrp[2 * tid]     = excl;
    lrp[2 * tid + 1] = excl + a0;
    __syncthreads();

    // ---- within-bucket counting sort by DESCENDING degree -> perml ----
    const int ra   = r0 + 2 * tid;
    const int bin0 = (DBINS - 1) - ((a0 < DBINS - 1) ? a0 : (DBINS - 1));
    const int bin1 = (DBINS - 1) - ((a1 < DBINS - 1) ? a1 : (DBINS - 1));
    if (ra < NN)     atomicAdd(&dhist[bin0], 1);
    if (ra + 1 < NN) atomicAdd(&dhist[bin1], 1);
    __syncthreads();
    ssum[tid] = (tid < DBINS) ? dhist[tid] : 0;
    __syncthreads();
    for (int off = 1; off < DBINS; off <<= 1) {
        int x = (tid >= off) ? ssum[tid - off] : 0;
        __syncthreads();
        ssum[tid] += x;
        __syncthreads();
    }
    if (tid < DBINS) { dbase[tid] = ssum[tid] - dhist[tid]; dhist[tid] = 0; }
    __syncthreads();
    if (ra < NN)     perml[dbase[bin0] + atomicAdd(&dhist[bin0], 1)] = 2 * tid;
    if (ra + 1 < NN) perml[dbase[bin1] + atomicAdd(&dhist[bin1], 1)] = 2 * tid + 1;
    __syncthreads();

    // ---- emit packed rinfo per perm slot ----
    for (int j = tid; j < RB; j += 256) {
        const int rl = perml[j];
        int2 out;
        if (rl >= 0) {
            int dg = rcnt[rl]; if (dg > 0xFFF) dg = 0xFFF;
            out = make_int2(s + lrp[rl], (r0 + rl) | (dg << 19));
        } else {
            out = make_int2(0, -1);
        }
        rinfo[r0 + j] = out;
    }

    for (int i = s + tid; i < e; i += 256) {
        const int v  = pairs[i];
        const int rl = (v >> 23) & (RB - 1);
        const int c  = v & 0x7FFFF;
        const ushort8v* ep = reinterpret_cast<const ushort8v*>(eb + (size_t)c * ED);
        const ushort8v q0 = ep[0], q1 = ep[1];
        const float* er = estage + rl * ED;
        float d = 0.0f;
#pragma unroll
        for (int j = 0; j < 8; ++j) d += bf2f(q0[j]) * er[j];
#pragma unroll
        for (int j = 0; j < 8; ++j) d += bf2f(q1[j]) * er[j + 8];
        const int o   = atomicAdd(&wq2[rl], 1);
        const int pos = s + lrp[rl] + o;
        epacked[pos] = make_int2(v & 0x7FFFFF, __float_as_int(d));
    }
}

// ---------------------------------------------------------------------------
// Fused attention, row-level software pipeline: each 8-lane group owns IT=4
// rows (slots base+it*32+gl; 8 contiguous deg-similar slots per wave per it).
// Steady state per row: the NEXT row's epacked batch is asm-prefetched before
// this row's single vmcnt(0) drain (completes it for free); this row's yrf +
// epilogue operand (emb0 / old io) are asm-issued before the batch loads
// (hidden under the same drain). Exposed chain per row ~1.5K cycles vs ~2.8K
// in R7 (R7 counters: VALUBusy 31%, HBM 42%, occupancy 28% -> still latency).
//   out = 0.5*(sum e0*y[c])/d0 + 0.5*(sum e1*y[c])/d1
// LAYER 0 epilogue: in-register LayerNorm(out1) -> yb_next; io=(emb0+out1)/3.
// LAYER 1 epilogue: io += out2/3 -> final mean in d_out.
// ---------------------------------------------------------------------------
template <int LAYER>
__global__ __launch_bounds__(256, 4)   // allow up to 128 VGPR
void attn_row_kernel(const bf16* __restrict__ yb,
                     const int2* __restrict__ rinfo,
                     const int2* __restrict__ epacked,
                     const float* __restrict__ lambda0,
                     const float* __restrict__ pemb,
                     const float* __restrict__ user_emb,
                     const float* __restrict__ item_emb,
                     bf16* __restrict__ yb_next,
                     float* __restrict__ io)
{
    __shared__ float e1tab[NP];
    if (threadIdx.x < NP)
        e1tab[threadIdx.x] = __expf(pemb[LAYER * NP + threadIdx.x]);
    __syncthreads();

    const int tid  = (int)threadIdx.x;
    const int gl   = tid >> 3;                    // group in block, 0..31
    const int sub  = tid & 7;
    const int lane = tid & 63;
    const int base = (int)blockIdx.x * (32 * IT);

    const float lam = __expf(lambda0[LAYER]);
    const bf16*  ybs = yb + (size_t)sub * 8;      // lane's dim-slice base
    const int2v* ep2 = reinterpret_cast<const int2v*>(epacked);

    // all IT rinfo up front (coalesced, independent)
    int2 ri[IT];
#pragma unroll
    for (int it = 0; it < IT; ++it) ri[it] = rinfo[base + it * 32 + gl];

    // prime the pipeline: epacked batch of row 0
    // (unguarded lane loads; lanes sub>=deg are zero-masked at use)
    int2v myv_n;
    {
        const int2v* mp = ep2 + ri[0].x + sub;
        asm volatile("global_load_dwordx2 %0, %1, off" : "=v"(myv_n) : "v"(mp));
        asm volatile("s_waitcnt vmcnt(0)" : "+v"(myv_n));
    }

#pragma unroll
    for (int it = 0; it < IT; ++it) {
        const int2 ric   = ri[it];
        const bool valid = (ric.y >= 0);
        const int r      = valid ? (ric.y & 0x7FFFF) : 0;
        const int deg    = valid ? ((ric.y >> 19) & 0xFFF) : 0;
        const int start  = ric.x;

        int2v myv = myv_n;
        if (sub >= deg) { myv[0] = 0; myv[1] = 0; }   // mask garbage lanes

        // broadcast the batch's (v, edot) to all lanes of the group
        int   vv[8];
        float ee[8];
#pragma unroll
        for (int kk = 0; kk < 8; ++kk) {
            const int src = (lane & ~7) + kk;
            vv[kk] = __shfl(myv[0], src, 64);
            ee[kk] = __int_as_float(__shfl(myv[1], src, 64));
        }
        const int nb = (deg < 8) ? deg : 8;

        // own-iteration loads, hidden under the batch drain:
        // yrf row + epilogue operand (emb0 for L0, old io for L1)
        ushort8v yru;
        float4v em_lo, em_hi;
        {
            const bf16* yp = ybs + (size_t)r * HD;
            asm volatile("global_load_dwordx4 %0, %1, off" : "=v"(yru) : "v"(yp));
            const float* ep = (LAYER == 0)
                ? (((r < NU) ? user_emb + (size_t)r * HD
                             : item_emb + (size_t)(r - NU) * HD) + sub * 8)
                : (io + (size_t)r * HD + sub * 8);
            asm volatile("global_load_dwordx4 %0, %1, off" : "=v"(em_lo) : "v"(ep));
            asm volatile("global_load_dwordx4 %0, %1, off" : "=v"(em_hi) : "v"(ep + 4));
        }

        // batch gather cluster (8 rows; padded lanes read row 0, harmless)
        const bf16* p0 = ybs + (size_t)(vv[0] & 0x7FFFF) * HD;
        const bf16* p1 = ybs + (size_t)(vv[1] & 0x7FFFF) * HD;
        const bf16* p2 = ybs + (size_t)(vv[2] & 0x7FFFF) * HD;
        const bf16* p3 = ybs + (size_t)(vv[3] & 0x7FFFF) * HD;
        const bf16* p4 = ybs + (size_t)(vv[4] & 0x7FFFF) * HD;
        const bf16* p5 = ybs + (size_t)(vv[5] & 0x7FFFF) * HD;
        const bf16* p6 = ybs + (size_t)(vv[6] & 0x7FFFF) * HD;
        const bf16* p7 = ybs + (size_t)(vv[7] & 0x7FFFF) * HD;
        ushort8v u0, u1, u2, u3, u4, u5, u6, u7;
        asm volatile("global_load_dwordx4 %0, %1, off" : "=v"(u0) : "v"(p0));
        asm volatile("global_load_dwordx4 %0, %1, off" : "=v"(u1) : "v"(p1));
        asm volatile("global_load_dwordx4 %0, %1, off" : "=v"(u2) : "v"(p2));
        asm volatile("global_load_dwordx4 %0, %1, off" : "=v"(u3) : "v"(p3));
        asm volatile("global_load_dwordx4 %0, %1, off" : "=v"(u4) : "v"(p4));
        asm volatile("global_load_dwordx4 %0, %1, off" : "=v"(u5) : "v"(p5));
        asm volatile("global_load_dwordx4 %0, %1, off" : "=v"(u6) : "v"(p6));
        asm volatile("global_load_dwordx4 %0, %1, off" : "=v"(u7) : "v"(p7));

        // cross-iteration prefetch: next row's epacked batch (needs ri only)
        if (it + 1 < IT) {
            const int2v* mp = ep2 + ri[it + 1].x + sub;
            asm volatile("global_load_dwordx2 %0, %1, off" : "=v"(myv_n) : "v"(mp));
        }

        // single drain per row: completes u0..u7, yru, em, myv_n (and the
        // previous row's fire-and-forget stores, overlapped with load latency)
        asm volatile("s_waitcnt vmcnt(0)"
                     : "+v"(u0), "+v"(u1), "+v"(u2), "+v"(u3),
                       "+v"(u4), "+v"(u5), "+v"(u6), "+v"(u7),
                       "+v"(yru), "+v"(em_lo), "+v"(em_hi), "+v"(myv_n));

        float yrf[8];
#pragma unroll
        for (int j = 0; j < 8; ++j) yrf[j] = bf2f(yru[j]);

        float U0[8], U1[8];
#pragma unroll
        for (int j = 0; j < 8; ++j) { U0[j] = 0.0f; U1[j] = 0.0f; }
        float d0 = 0.0f, d1 = 0.0f;

        auto consume = [&](const ushort8v& uc, int vk, float ek) {
            float yc[8];
            float sdot = 0.0f;
#pragma unroll
            for (int j = 0; j < 8; ++j) { yc[j] = bf2f(uc[j]); sdot += yrf[j] * yc[j]; }
            sdot += __shfl_xor(sdot, 1, 64);
            sdot += __shfl_xor(sdot, 2, 64);
            sdot += __shfl_xor(sdot, 4, 64);
            const float e0 = __expf(sdot * 0.125f + lam * ek);
            const float e1 = e1tab[(vk >> 19) & 15];
            d0 += e0; d1 += e1;
#pragma unroll
            for (int j = 0; j < 8; ++j) {
                U0[j] += e0 * yc[j];
                U1[j] += e1 * yc[j];
            }
        };
        if (nb > 0) consume(u0, vv[0], ee[0]);
        if (nb > 1) consume(u1, vv[1], ee[1]);
        if (nb > 2) consume(u2, vv[2], ee[2]);
        if (nb > 3) consume(u3, vv[3], ee[3]);
        if (nb > 4) consume(u4, vv[4], ee[4]);
        if (nb > 5) consume(u5, vv[5], ee[5]);
        if (nb > 6) consume(u6, vv[6], ee[6]);
        if (nb > 7) consume(u7, vv[7], ee[7]);

        // rare multi-batch tail (deg > 8, ~4% of rows; plain C path)
        for (int k0 = 8; k0 < deg; k0 += 8) {
            int2 mv = ((k0 + sub) < deg) ? epacked[start + k0 + sub]
                                         : make_int2(0, 0);
            int   vv2[8];
            float ee2[8];
#pragma unroll
            for (int kk = 0; kk < 8; ++kk) {
                const int src = (lane & ~7) + kk;
                vv2[kk] = __shfl(mv.x, src, 64);
                ee2[kk] = __int_as_float(__shfl(mv.y, src, 64));
            }
            const int nb2 = ((deg - k0) < 8) ? (deg - k0) : 8;
#pragma unroll
            for (int kk = 0; kk < 8; ++kk) {
                if (kk < nb2) {
                    ushort8v uc = *reinterpret_cast<const ushort8v*>(
                        ybs + (size_t)(vv2[kk] & 0x7FFFF) * HD);
                    consume(uc, vv2[kk], ee2[kk]);
                }
            }
        }

        const float i0 = deg ? 0.5f / d0 : 0.0f;
        const float i1 = deg ? 0.5f / d1 : 0.0f;
        float acc[8];
#pragma unroll
        for (int j = 0; j < 8; ++j) acc[j] = i0 * U0[j] + i1 * U1[j];

        float* iorow = io + (size_t)r * HD + sub * 8;
        if (LAYER == 0) {
            if (valid) {   // per-group uniform: LN shuffles stay intra-group
                float sm = 0.0f, sq = 0.0f;
#pragma unroll
                for (int j = 0; j < 8; ++j) { sm += acc[j]; sq += acc[j] * acc[j]; }
                sm += __shfl_xor(sm, 1, 64); sq += __shfl_xor(sq, 1, 64);
                sm += __shfl_xor(sm, 2, 64); sq += __shfl_xor(sq, 2, 64);
                sm += __shfl_xor(sm, 4, 64); sq += __shfl_xor(sq, 4, 64);
                const float mu  = sm * (1.0f / 64.0f);
                const float var = sq * (1.0f / 64.0f) - mu * mu;
                const float inv = rsqrtf(var + 1e-5f);
                ushort8v w;
#pragma unroll
                for (int j = 0; j < 8; ++j) w[j] = f2b((acc[j] - mu) * inv);
                *reinterpret_cast<ushort8v*>(yb_next + (size_t)r * HD + sub * 8) = w;

                const float third = 1.0f / 3.0f;
                float4v o0, o1;
                o0[0] = (em_lo[0] + acc[0]) * third; o0[1] = (em_lo[1] + acc[1]) * third;
                o0[2] = (em_lo[2] + acc[2]) * third; o0[3] = (em_lo[3] + acc[3]) * third;
                o1[0] = (em_hi[0] + acc[4]) * third; o1[1] = (em_hi[1] + acc[5]) * third;
                o1[2] = (em_hi[2] + acc[6]) * third; o1[3] = (em_hi[3] + acc[7]) * third;
                *reinterpret_cast<float4v*>(iorow)     = o0;
                *reinterpret_cast<float4v*>(iorow + 4) = o1;
            }
        } else {
            if (valid && deg > 0) {
                const float third = 1.0f / 3.0f;
                float4v o0, o1;
                o0[0] = em_lo[0] + acc[0] * third; o0[1] = em_lo[1] + acc[1] * third;
                o0[2] = em_lo[2] + acc[2] * third; o0[3] = em_lo[3] + acc[3] * third;
                o1[0] = em_hi[0] + acc[4] * third; o1[1] = em_hi[1] + acc[5] * third;
                o1[2] = em_hi[2] + acc[6] * third; o1[3] = em_hi[3] + acc[7] * third;
                *reinterpret_cast<float4v*>(iorow)     = o0;
                *reinterpret_cast<float4v*>(iorow + 4) = o1;
            }
        }
    }
}

extern "C" void kernel_launch(void* const* d_in, const int* in_sizes, int n_in,
                              void* d_out, int out_size, void* d_ws, size_t ws_size,
                              hipStream_t stream)
{
    const float* user_emb = (const float*)d_in[0];
    const float* item_emb = (const float*)d_in[1];
    const float* eigs     = (const float*)d_in[2];
    const float* lambda0  = (const float*)d_in[3];
    const float* pemb     = (const float*)d_in[4];
    const int*   indices  = (const int*)d_in[5];
    const int*   ptype    = (const int*)d_in[6];
    const int*   row = indices;
    const int*   col = indices + NE;

    float* io = (float*)d_out;                        // NN*HD fp32 accumulator
    char*  ws = (char*)d_ws;
    bf16* yb       = (bf16*)ws;                       // 38.4 MB
    bf16* yb2      = yb + (size_t)NN * HD;            // 38.4 MB
    bf16* eb       = yb2 + (size_t)NN * HD;           //  9.6 MB
    int*  pairs    = (int*)(eb + (size_t)NN * ED);    // NE      (5 MB)
    int2* epacked  = (int2*)(pairs + NE);             // NE int2 (10 MB)
    int2* rinfo    = epacked + NE;                    // NR8 int2 (2.4 MB)
    int*  bkt_cnt  = (int*)(rinfo + NR8);             // NBKT
    int*  bkt_base = bkt_cnt + NBKT;                  // NBKT+1
    int*  wq_bkt   = bkt_base + NBKT + 1;             // NBKT
    // total ws ~ 104 MB

    const dim3 blk(256);
    const int gridAttn = NR8 / (32 * IT);             // 2344 blocks, 4 rows/group

    // ---- LayerNorm + bf16 eig table (eb consumed by bkt_sort) ----
    ln_kernel<<<(NN * 8 + 255) / 256, blk, 0, stream>>>(user_emb, item_emb, eigs, yb, eb);

    // ---- CSR build: two-level binned counting sort + desc-degree perm ----
    hipMemsetAsync(bkt_cnt, 0, NBKT * sizeof(int), stream);
    bkt_count_kernel<<<A_BLOCKS, blk, 0, stream>>>(row, bkt_cnt);
    bkt_scan_kernel<<<1, 1024, 0, stream>>>(bkt_cnt, bkt_base, wq_bkt);
    bkt_scatter_kernel<<<A_BLOCKS, blk, 0, stream>>>(row, col, ptype, wq_bkt, pairs);
    bkt_sort_kernel<<<NBKT, blk, 0, stream>>>(bkt_base, pairs, eigs, eb,
                                              rinfo, epacked);

    // ---- layer 0 (attn fuses ln2 + final-mean prep) ----
    attn_row_kernel<0><<<gridAttn, blk, 0, stream>>>(yb, rinfo, epacked,
                                                     lambda0, pemb, user_emb,
                                                     item_emb, yb2, io);
    // ---- layer 1 (adds out2/3 -> final mean in d_out) ----
    attn_row_kernel<1><<<gridAttn, blk, 0, stream>>>(yb2, rinfo, epacked,
                                                     lambda0, pemb, user_emb,
                                                     item_emb, nullptr, io);
}

// Round 9
// 386.774 us; speedup vs baseline: 1.0726x; 1.0371x over previous
//
#include <hip/hip_runtime.h>
#include <hip/hip_bf16.h>

#define HD 64
#define ED 16
#define NU 100000
#define NI 200000
#define NN 300000
#define NE 1250000
#define NP 14

#define RB 512                         // rows per bucket (9 bits)
#define NBKT ((NN + RB - 1) / RB)      // 586 buckets
#define NR8 (NBKT * RB)                // 300032 perm slots (tail invalid)
#define BCAP 2432                      // fixed bucket capacity (mean 2133 + 6.5 sigma)
#define A_ITEMS 16
#define A_CHUNK (256 * A_ITEMS)        // 4096 edges per binning block
#define A_BLOCKS ((NE + A_CHUNK - 1) / A_CHUNK)   // 306
#define DBINS 64                       // degree-sort bins (bin clamped at 63)
#define IT 4                           // rows per group (pipelined)

typedef __hip_bfloat16 bf16;
typedef unsigned short ushort8v __attribute__((ext_vector_type(8)));
typedef float  float4v __attribute__((ext_vector_type(4)));
typedef int    int2v   __attribute__((ext_vector_type(2)));

__device__ __forceinline__ float bf2f(unsigned short u) {
    union { unsigned int i; float f; } c; c.i = ((unsigned int)u) << 16; return c.f;
}
__device__ __forceinline__ unsigned short f2b(float x) {
    bf16 h = __float2bfloat16(x);
    unsigned short u; __builtin_memcpy(&u, &h, 2); return u;
}

// ---------------------------------------------------------------------------
// LayerNorm of input embeddings, 8-lane group per row (lane = 8 dims).
// (eig conversion dropped: bkt_sort now gathers fp32 eigs directly)
// ---------------------------------------------------------------------------
__global__ void ln_kernel(const float* __restrict__ user_emb,
                          const float* __restrict__ item_emb,
                          bf16* __restrict__ yb)
{
    const int tid = blockIdx.x * blockDim.x + threadIdx.x;
    const int r   = tid >> 3;
    const int sub = tid & 7;
    if (r >= NN) return;
    const float* src = (r < NU) ? user_emb + (size_t)r * HD
                                : item_emb + (size_t)(r - NU) * HD;
    const float4 lo = *reinterpret_cast<const float4*>(src + sub * 8);
    const float4 hi = *reinterpret_cast<const float4*>(src + sub * 8 + 4);
    float x[8] = {lo.x, lo.y, lo.z, lo.w, hi.x, hi.y, hi.z, hi.w};

    float sm = 0.0f, sq = 0.0f;
#pragma unroll
    for (int j = 0; j < 8; ++j) { sm += x[j]; sq += x[j] * x[j]; }
    sm += __shfl_xor(sm, 1, 64); sq += __shfl_xor(sq, 1, 64);
    sm += __shfl_xor(sm, 2, 64); sq += __shfl_xor(sq, 2, 64);
    sm += __shfl_xor(sm, 4, 64); sq += __shfl_xor(sq, 4, 64);
    const float mu  = sm * (1.0f / 64.0f);
    const float var = sq * (1.0f / 64.0f) - mu * mu;
    const float inv = rsqrtf(var + 1e-5f);

    ushort8v w;
#pragma unroll
    for (int j = 0; j < 8; ++j) w[j] = f2b((x[j] - mu) * inv);
    *reinterpret_cast<ushort8v*>(yb + (size_t)r * HD + sub * 8) = w;
}

// --------- single-pass binning: fixed-stride buckets (no count/scan) -------
// Each block histograms its 4096-edge chunk in LDS, reserves per-bucket
// space with ONE global atomicAdd per (block,bucket), scatters packed pairs
// into bucket region [b*BCAP, (b+1)*BCAP). Overflow (p ~ 2e-8) guarded.
__global__ void bkt_scatter_kernel(const int* __restrict__ row,
                                   const int* __restrict__ col,
                                   const int* __restrict__ pt,
                                   int* __restrict__ wq_bkt,
                                   int* __restrict__ pairs)
{
    __shared__ int hist[NBKT];
    __shared__ int rbase[NBKT];
    __shared__ int roff[NBKT];
    const int tid = threadIdx.x;
    for (int j = tid; j < NBKT; j += 256) { hist[j] = 0; roff[j] = 0; }
    __syncthreads();

    const int base = blockIdx.x * A_CHUNK;
#pragma unroll
    for (int i = 0; i < A_ITEMS; ++i) {
        const int idx = base + i * 256 + tid;
        if (idx < NE) atomicAdd(&hist[row[idx] >> 9], 1);
    }
    __syncthreads();
    for (int j = tid; j < NBKT; j += 256) {
        const int h = hist[j];
        if (h) rbase[j] = atomicAdd(&wq_bkt[j], h);
    }
    __syncthreads();
#pragma unroll
    for (int i = 0; i < A_ITEMS; ++i) {
        const int idx = base + i * 256 + tid;
        if (idx < NE) {
            const int r = row[idx];
            const int b = r >> 9;
            const int v = col[idx] | (pt[idx] << 19) | ((r & (RB - 1)) << 23);
            const int o   = atomicAdd(&roff[b], 1);
            const int rel = rbase[b] + o;
            if (rel < BCAP) pairs[(size_t)b * BCAP + rel] = v;
        }
    }
}

// --------- stage B: per-bucket sort by row + eig-dot precompute ------------
// One block per bucket (fixed-stride region). Row-side eigs staged fp32 in
// LDS; col-side gathered fp32 (64 B/edge, L2/L3-resident). Emits
// DESCENDING-degree perm slots as PACKED rinfo:
//   rinfo[slot] = { epacked_start, r | deg<<19 }   (invalid slot: y = -1)
__global__ void bkt_sort_kernel(const int* __restrict__ wq_bkt,
                                const int* __restrict__ pairs,
                                const float* __restrict__ eigs,
                                int2* __restrict__ rinfo,
                                int2* __restrict__ epacked)
{
    __shared__ int rcnt[RB], lrp[RB], wq2[RB], ssum[256];
    __shared__ int dhist[DBINS], dbase[DBINS];
    __shared__ int perml[RB];
    __shared__ float estage[RB * ED];
    const int tid  = threadIdx.x;
    const int b    = blockIdx.x;
    const int r0   = b * RB;
    const int sbase = b * BCAP;
    int cntb = wq_bkt[b]; if (cntb > BCAP) cntb = BCAP;

    for (int j = tid; j < RB; j += 256) { rcnt[j] = 0; wq2[j] = 0; perml[j] = -1; }
    for (int j = tid; j < DBINS; j += 256) dhist[j] = 0;
    for (int k = tid; k < RB * ED; k += 256) {
        const int g = r0 * ED + k;
        estage[k] = (g < NN * ED) ? eigs[g] : 0.0f;
    }
    __syncthreads();

    for (int i = tid; i < cntb; i += 256)
        atomicAdd(&rcnt[(pairs[sbase + i] >> 23) & (RB - 1)], 1);
    __syncthreads();

    const int a0 = rcnt[2 * tid], a1 = rcnt[2 * tid + 1];
    ssum[tid] = a0 + a1;
    __syncthreads();
    for (int off = 1; off < 256; off <<= 1) {
        int x = (tid >= off) ? ssum[tid - off] : 0;
        __syncthreads();
        ssum[tid] += x;
        __syncthreads();
    }
    const int excl = ssum[tid] - (a0 + a1);
    lrp[2 * tid]     = excl;
    lrp[2 * tid + 1] = excl + a0;
    __syncthreads();

    // ---- within-bucket counting sort by DESCENDING degree -> perml ----
    const int ra   = r0 + 2 * tid;
    const int bin0 = (DBINS - 1) - ((a0 < DBINS - 1) ? a0 : (DBINS - 1));
    const int bin1 = (DBINS - 1) - ((a1 < DBINS - 1) ? a1 : (DBINS - 1));
    if (ra < NN)     atomicAdd(&dhist[bin0], 1);
    if (ra + 1 < NN) atomicAdd(&dhist[bin1], 1);
    __syncthreads();
    ssum[tid] = (tid < DBINS) ? dhist[tid] : 0;
    __syncthreads();
    for (int off = 1; off < DBINS; off <<= 1) {
        int x = (tid >= off) ? ssum[tid - off] : 0;
        __syncthreads();
        ssum[tid] += x;
        __syncthreads();
    }
    if (tid < DBINS) { dbase[tid] = ssum[tid] - dhist[tid]; dhist[tid] = 0; }
    __syncthreads();
    if (ra < NN)     perml[dbase[bin0] + atomicAdd(&dhist[bin0], 1)] = 2 * tid;
    if (ra + 1 < NN) perml[dbase[bin1] + atomicAdd(&dhist[bin1], 1)] = 2 * tid + 1;
    __syncthreads();

    // ---- emit packed rinfo per perm slot ----
    for (int j = tid; j < RB; j += 256) {
        const int rl = perml[j];
        int2 out;
        if (rl >= 0) {
            int dg = rcnt[rl]; if (dg > 0xFFF) dg = 0xFFF;
            out = make_int2(sbase + lrp[rl], (r0 + rl) | (dg << 19));
        } else {
            out = make_int2(0, -1);
        }
        rinfo[r0 + j] = out;
    }

    for (int i = tid; i < cntb; i += 256) {
        const int v  = pairs[sbase + i];
        const int rl = (v >> 23) & (RB - 1);
        const int c  = v & 0x7FFFF;
        const float4* ep = reinterpret_cast<const float4*>(eigs + (size_t)c * ED);
        const float4 q0 = ep[0], q1 = ep[1], q2 = ep[2], q3 = ep[3];
        const float* er = estage + rl * ED;
        float d = q0.x * er[0]  + q0.y * er[1]  + q0.z * er[2]  + q0.w * er[3]
                + q1.x * er[4]  + q1.y * er[5]  + q1.z * er[6]  + q1.w * er[7]
                + q2.x * er[8]  + q2.y * er[9]  + q2.z * er[10] + q2.w * er[11]
                + q3.x * er[12] + q3.y * er[13] + q3.z * er[14] + q3.w * er[15];
        const int o   = atomicAdd(&wq2[rl], 1);
        const int pos = sbase + lrp[rl] + o;
        epacked[pos] = make_int2(v & 0x7FFFFF, __float_as_int(d));
    }
}

// ---------------------------------------------------------------------------
// Fused attention, row-level software pipeline (unchanged from R8: VGPR=64
// shows the 11-load in-flight window is honored; attn now sits at ~1.9x its
// HBM compulsory floor in a mixed VALU+L3-gather regime).
//   out = 0.5*(sum e0*y[c])/d0 + 0.5*(sum e1*y[c])/d1
// LAYER 0 epilogue: in-register LayerNorm(out1) -> yb_next; io=(emb0+out1)/3.
// LAYER 1 epilogue: io += out2/3 -> final mean in d_out.
// ---------------------------------------------------------------------------
template <int LAYER>
__global__ __launch_bounds__(256, 4)   // allow up to 128 VGPR
void attn_row_kernel(const bf16* __restrict__ yb,
                     const int2* __restrict__ rinfo,
                     const int2* __restrict__ epacked,
                     const float* __restrict__ lambda0,
                     const float* __restrict__ pemb,
                     const float* __restrict__ user_emb,
                     const float* __restrict__ item_emb,
                     bf16* __restrict__ yb_next,
                     float* __restrict__ io)
{
    __shared__ float e1tab[NP];
    if (threadIdx.x < NP)
        e1tab[threadIdx.x] = __expf(pemb[LAYER * NP + threadIdx.x]);
    __syncthreads();

    const int tid  = (int)threadIdx.x;
    const int gl   = tid >> 3;                    // group in block, 0..31
    const int sub  = tid & 7;
    const int lane = tid & 63;
    const int base = (int)blockIdx.x * (32 * IT);

    const float lam = __expf(lambda0[LAYER]);
    const bf16*  ybs = yb + (size_t)sub * 8;      // lane's dim-slice base
    const int2v* ep2 = reinterpret_cast<const int2v*>(epacked);

    // all IT rinfo up front (coalesced, independent)
    int2 ri[IT];
#pragma unroll
    for (int it = 0; it < IT; ++it) ri[it] = rinfo[base + it * 32 + gl];

    // prime the pipeline: epacked batch of row 0
    int2v myv_n;
    {
        const int2v* mp = ep2 + ri[0].x + sub;
        asm volatile("global_load_dwordx2 %0, %1, off" : "=v"(myv_n) : "v"(mp));
        asm volatile("s_waitcnt vmcnt(0)" : "+v"(myv_n));
    }

#pragma unroll
    for (int it = 0; it < IT; ++it) {
        const int2 ric   = ri[it];
        const bool valid = (ric.y >= 0);
        const int r      = valid ? (ric.y & 0x7FFFF) : 0;
        const int deg    = valid ? ((ric.y >> 19) & 0xFFF) : 0;
        const int start  = ric.x;

        int2v myv = myv_n;
        if (sub >= deg) { myv[0] = 0; myv[1] = 0; }   // mask garbage lanes

        // broadcast the batch's (v, edot) to all lanes of the group
        int   vv[8];
        float ee[8];
#pragma unroll
        for (int kk = 0; kk < 8; ++kk) {
            const int src = (lane & ~7) + kk;
            vv[kk] = __shfl(myv[0], src, 64);
            ee[kk] = __int_as_float(__shfl(myv[1], src, 64));
        }
        const int nb = (deg < 8) ? deg : 8;

        // own-iteration loads, hidden under the batch drain:
        // yrf row + epilogue operand (emb0 for L0, old io for L1)
        ushort8v yru;
        float4v em_lo, em_hi;
        {
            const bf16* yp = ybs + (size_t)r * HD;
            asm volatile("global_load_dwordx4 %0, %1, off" : "=v"(yru) : "v"(yp));
            const float* ep = (LAYER == 0)
                ? (((r < NU) ? user_emb + (size_t)r * HD
                             : item_emb + (size_t)(r - NU) * HD) + sub * 8)
                : (io + (size_t)r * HD + sub * 8);
            asm volatile("global_load_dwordx4 %0, %1, off" : "=v"(em_lo) : "v"(ep));
            asm volatile("global_load_dwordx4 %0, %1, off" : "=v"(em_hi) : "v"(ep + 4));
        }

        // batch gather cluster (8 rows; padded lanes read row 0, harmless)
        const bf16* p0 = ybs + (size_t)(vv[0] & 0x7FFFF) * HD;
        const bf16* p1 = ybs + (size_t)(vv[1] & 0x7FFFF) * HD;
        const bf16* p2 = ybs + (size_t)(vv[2] & 0x7FFFF) * HD;
        const bf16* p3 = ybs + (size_t)(vv[3] & 0x7FFFF) * HD;
        const bf16* p4 = ybs + (size_t)(vv[4] & 0x7FFFF) * HD;
        const bf16* p5 = ybs + (size_t)(vv[5] & 0x7FFFF) * HD;
        const bf16* p6 = ybs + (size_t)(vv[6] & 0x7FFFF) * HD;
        const bf16* p7 = ybs + (size_t)(vv[7] & 0x7FFFF) * HD;
        ushort8v u0, u1, u2, u3, u4, u5, u6, u7;
        asm volatile("global_load_dwordx4 %0, %1, off" : "=v"(u0) : "v"(p0));
        asm volatile("global_load_dwordx4 %0, %1, off" : "=v"(u1) : "v"(p1));
        asm volatile("global_load_dwordx4 %0, %1, off" : "=v"(u2) : "v"(p2));
        asm volatile("global_load_dwordx4 %0, %1, off" : "=v"(u3) : "v"(p3));
        asm volatile("global_load_dwordx4 %0, %1, off" : "=v"(u4) : "v"(p4));
        asm volatile("global_load_dwordx4 %0, %1, off" : "=v"(u5) : "v"(p5));
        asm volatile("global_load_dwordx4 %0, %1, off" : "=v"(u6) : "v"(p6));
        asm volatile("global_load_dwordx4 %0, %1, off" : "=v"(u7) : "v"(p7));

        // cross-iteration prefetch: next row's epacked batch (needs ri only)
        if (it + 1 < IT) {
            const int2v* mp = ep2 + ri[it + 1].x + sub;
            asm volatile("global_load_dwordx2 %0, %1, off" : "=v"(myv_n) : "v"(mp));
        }

        // single drain per row
        asm volatile("s_waitcnt vmcnt(0)"
                     : "+v"(u0), "+v"(u1), "+v"(u2), "+v"(u3),
                       "+v"(u4), "+v"(u5), "+v"(u6), "+v"(u7),
                       "+v"(yru), "+v"(em_lo), "+v"(em_hi), "+v"(myv_n));

        float yrf[8];
#pragma unroll
        for (int j = 0; j < 8; ++j) yrf[j] = bf2f(yru[j]);

        float U0[8], U1[8];
#pragma unroll
        for (int j = 0; j < 8; ++j) { U0[j] = 0.0f; U1[j] = 0.0f; }
        float d0 = 0.0f, d1 = 0.0f;

        auto consume = [&](const ushort8v& uc, int vk, float ek) {
            float yc[8];
            float sdot = 0.0f;
#pragma unroll
            for (int j = 0; j < 8; ++j) { yc[j] = bf2f(uc[j]); sdot += yrf[j] * yc[j]; }
            sdot += __shfl_xor(sdot, 1, 64);
            sdot += __shfl_xor(sdot, 2, 64);
            sdot += __shfl_xor(sdot, 4, 64);
            const float e0 = __expf(sdot * 0.125f + lam * ek);
            const float e1 = e1tab[(vk >> 19) & 15];
            d0 += e0; d1 += e1;
#pragma unroll
            for (int j = 0; j < 8; ++j) {
                U0[j] += e0 * yc[j];
                U1[j] += e1 * yc[j];
            }
        };
        if (nb > 0) consume(u0, vv[0], ee[0]);
        if (nb > 1) consume(u1, vv[1], ee[1]);
        if (nb > 2) consume(u2, vv[2], ee[2]);
        if (nb > 3) consume(u3, vv[3], ee[3]);
        if (nb > 4) consume(u4, vv[4], ee[4]);
        if (nb > 5) consume(u5, vv[5], ee[5]);
        if (nb > 6) consume(u6, vv[6], ee[6]);
        if (nb > 7) consume(u7, vv[7], ee[7]);

        // rare multi-batch tail (deg > 8, ~4% of rows; plain C path)
        for (int k0 = 8; k0 < deg; k0 += 8) {
            int2 mv = ((k0 + sub) < deg) ? epacked[start + k0 + sub]
                                         : make_int2(0, 0);
            int   vv2[8];
            float ee2[8];
#pragma unroll
            for (int kk = 0; kk < 8; ++kk) {
                const int src = (lane & ~7) + kk;
                vv2[kk] = __shfl(mv.x, src, 64);
                ee2[kk] = __int_as_float(__shfl(mv.y, src, 64));
            }
            const int nb2 = ((deg - k0) < 8) ? (deg - k0) : 8;
#pragma unroll
            for (int kk = 0; kk < 8; ++kk) {
                if (kk < nb2) {
                    ushort8v uc = *reinterpret_cast<const ushort8v*>(
                        ybs + (size_t)(vv2[kk] & 0x7FFFF) * HD);
                    consume(uc, vv2[kk], ee2[kk]);
                }
            }
        }

        const float i0 = deg ? 0.5f / d0 : 0.0f;
        const float i1 = deg ? 0.5f / d1 : 0.0f;
        float acc[8];
#pragma unroll
        for (int j = 0; j < 8; ++j) acc[j] = i0 * U0[j] + i1 * U1[j];

        float* iorow = io + (size_t)r * HD + sub * 8;
        if (LAYER == 0) {
            if (valid) {   // per-group uniform: LN shuffles stay intra-group
                float sm = 0.0f, sq = 0.0f;
#pragma unroll
                for (int j = 0; j < 8; ++j) { sm += acc[j]; sq += acc[j] * acc[j]; }
                sm += __shfl_xor(sm, 1, 64); sq += __shfl_xor(sq, 1, 64);
                sm += __shfl_xor(sm, 2, 64); sq += __shfl_xor(sq, 2, 64);
                sm += __shfl_xor(sm, 4, 64); sq += __shfl_xor(sq, 4, 64);
                const float mu  = sm * (1.0f / 64.0f);
                const float var = sq * (1.0f / 64.0f) - mu * mu;
                const float inv = rsqrtf(var + 1e-5f);
                ushort8v w;
#pragma unroll
                for (int j = 0; j < 8; ++j) w[j] = f2b((acc[j] - mu) * inv);
                *reinterpret_cast<ushort8v*>(yb_next + (size_t)r * HD + sub * 8) = w;

                const float third = 1.0f / 3.0f;
                float4v o0, o1;
                o0[0] = (em_lo[0] + acc[0]) * third; o0[1] = (em_lo[1] + acc[1]) * third;
                o0[2] = (em_lo[2] + acc[2]) * third; o0[3] = (em_lo[3] + acc[3]) * third;
                o1[0] = (em_hi[0] + acc[4]) * third; o1[1] = (em_hi[1] + acc[5]) * third;
                o1[2] = (em_hi[2] + acc[6]) * third; o1[3] = (em_hi[3] + acc[7]) * third;
                *reinterpret_cast<float4v*>(iorow)     = o0;
                *reinterpret_cast<float4v*>(iorow + 4) = o1;
            }
        } else {
            if (valid && deg > 0) {
                const float third = 1.0f / 3.0f;
                float4v o0, o1;
                o0[0] = em_lo[0] + acc[0] * third; o0[1] = em_lo[1] + acc[1] * third;
                o0[2] = em_lo[2] + acc[2] * third; o0[3] = em_lo[3] + acc[3] * third;
                o1[0] = em_hi[0] + acc[4] * third; o1[1] = em_hi[1] + acc[5] * third;
                o1[2] = em_hi[2] + acc[6] * third; o1[3] = em_hi[3] + acc[7] * third;
                *reinterpret_cast<float4v*>(iorow)     = o0;
                *reinterpret_cast<float4v*>(iorow + 4) = o1;
            }
        }
    }
}

extern "C" void kernel_launch(void* const* d_in, const int* in_sizes, int n_in,
                              void* d_out, int out_size, void* d_ws, size_t ws_size,
                              hipStream_t stream)
{
    const float* user_emb = (const float*)d_in[0];
    const float* item_emb = (const float*)d_in[1];
    const float* eigs     = (const float*)d_in[2];
    const float* lambda0  = (const float*)d_in[3];
    const float* pemb     = (const float*)d_in[4];
    const int*   indices  = (const int*)d_in[5];
    const int*   ptype    = (const int*)d_in[6];
    const int*   row = indices;
    const int*   col = indices + NE;

    float* io = (float*)d_out;                        // NN*HD fp32 accumulator
    char*  ws = (char*)d_ws;
    bf16* yb       = (bf16*)ws;                       // 38.4 MB
    bf16* yb2      = yb + (size_t)NN * HD;            // 38.4 MB
    int*  pairs    = (int*)(yb2 + (size_t)NN * HD);   // NBKT*BCAP (5.7 MB)
    int2* epacked  = (int2*)(pairs + (size_t)NBKT * BCAP);  // NBKT*BCAP int2 (11.4 MB)
    int2* rinfo    = epacked + (size_t)NBKT * BCAP;   // NR8 int2 (2.4 MB)
    int*  wq_bkt   = (int*)(rinfo + NR8);             // NBKT
    // total ws ~ 96.3 MB

    const dim3 blk(256);
    const int gridAttn = NR8 / (32 * IT);             // 2344 blocks, 4 rows/group

    // ---- LayerNorm (independent of CSR build) ----
    ln_kernel<<<(NN * 8 + 255) / 256, blk, 0, stream>>>(user_emb, item_emb, yb);

    // ---- CSR build: single-pass fixed-stride binning + sort ----
    hipMemsetAsync(wq_bkt, 0, NBKT * sizeof(int), stream);
    bkt_scatter_kernel<<<A_BLOCKS, blk, 0, stream>>>(row, col, ptype, wq_bkt, pairs);
    bkt_sort_kernel<<<NBKT, blk, 0, stream>>>(wq_bkt, pairs, eigs, rinfo, epacked);

    // ---- layer 0 (attn fuses ln2 + final-mean prep) ----
    attn_row_kernel<0><<<gridAttn, blk, 0, stream>>>(yb, rinfo, epacked,
                                                     lambda0, pemb, user_emb,
                                                     item_emb, yb2, io);
    // ---- layer 1 (adds out2/3 -> final mean in d_out) ----
    attn_row_kernel<1><<<gridAttn, blk, 0, stream>>>(yb2, rinfo, epacked,
                                                     lambda0, pemb, user_emb,
                                                     item_emb, nullptr, io);
}

// Round 10
// 376.474 us; speedup vs baseline: 1.1020x; 1.0274x over previous
//
#include <hip/hip_runtime.h>
#include <hip/hip_bf16.h>

#define HD 64
#define ED 16
#define NU 100000
#define NI 200000
#define NN 300000
#define NE 1250000
#define NP 14

#define RB 512                         // rows per bucket (9 bits)
#define NBKT ((NN + RB - 1) / RB)      // 586 buckets
#define NR8 (NBKT * RB)                // 300032 perm slots (tail invalid)
#define BCAP 2432                      // fixed bucket capacity (mean 2133 + 6.5 sigma)
#define A_ITEMS 16
#define A_CHUNK (256 * A_ITEMS)        // 4096 edges per binning block
#define A_BLOCKS ((NE + A_CHUNK - 1) / A_CHUNK)   // 306
#define DBINS 64                       // degree-sort bins (bin clamped at 63)
#define IT 4                           // rows per group (pipelined)

typedef __hip_bfloat16 bf16;
typedef unsigned short ushort8v __attribute__((ext_vector_type(8)));
typedef float  float4v __attribute__((ext_vector_type(4)));
typedef float  float2v __attribute__((ext_vector_type(2)));
typedef int    int2v   __attribute__((ext_vector_type(2)));

__device__ __forceinline__ float bf2f(unsigned short u) {
    union { unsigned int i; float f; } c; c.i = ((unsigned int)u) << 16; return c.f;
}
__device__ __forceinline__ unsigned short f2b(float x) {
    bf16 h = __float2bfloat16(x);
    unsigned short u; __builtin_memcpy(&u, &h, 2); return u;
}

// ---------------------------------------------------------------------------
// LayerNorm of input embeddings, 8-lane group per row (lane = 8 dims).
// ---------------------------------------------------------------------------
__global__ void ln_kernel(const float* __restrict__ user_emb,
                          const float* __restrict__ item_emb,
                          bf16* __restrict__ yb)
{
    const int tid = blockIdx.x * blockDim.x + threadIdx.x;
    const int r   = tid >> 3;
    const int sub = tid & 7;
    if (r >= NN) return;
    const float* src = (r < NU) ? user_emb + (size_t)r * HD
                                : item_emb + (size_t)(r - NU) * HD;
    const float4 lo = *reinterpret_cast<const float4*>(src + sub * 8);
    const float4 hi = *reinterpret_cast<const float4*>(src + sub * 8 + 4);
    float x[8] = {lo.x, lo.y, lo.z, lo.w, hi.x, hi.y, hi.z, hi.w};

    float sm = 0.0f, sq = 0.0f;
#pragma unroll
    for (int j = 0; j < 8; ++j) { sm += x[j]; sq += x[j] * x[j]; }
    sm += __shfl_xor(sm, 1, 64); sq += __shfl_xor(sq, 1, 64);
    sm += __shfl_xor(sm, 2, 64); sq += __shfl_xor(sq, 2, 64);
    sm += __shfl_xor(sm, 4, 64); sq += __shfl_xor(sq, 4, 64);
    const float mu  = sm * (1.0f / 64.0f);
    const float var = sq * (1.0f / 64.0f) - mu * mu;
    const float inv = rsqrtf(var + 1e-5f);

    ushort8v w;
#pragma unroll
    for (int j = 0; j < 8; ++j) w[j] = f2b((x[j] - mu) * inv);
    *reinterpret_cast<ushort8v*>(yb + (size_t)r * HD + sub * 8) = w;
}

// --------- single-pass binning: fixed-stride buckets (no count/scan) -------
__global__ void bkt_scatter_kernel(const int* __restrict__ row,
                                   const int* __restrict__ col,
                                   const int* __restrict__ pt,
                                   int* __restrict__ wq_bkt,
                                   int* __restrict__ pairs)
{
    __shared__ int hist[NBKT];
    __shared__ int rbase[NBKT];
    __shared__ int roff[NBKT];
    const int tid = threadIdx.x;
    for (int j = tid; j < NBKT; j += 256) { hist[j] = 0; roff[j] = 0; }
    __syncthreads();

    const int base = blockIdx.x * A_CHUNK;
#pragma unroll
    for (int i = 0; i < A_ITEMS; ++i) {
        const int idx = base + i * 256 + tid;
        if (idx < NE) atomicAdd(&hist[row[idx] >> 9], 1);
    }
    __syncthreads();
    for (int j = tid; j < NBKT; j += 256) {
        const int h = hist[j];
        if (h) rbase[j] = atomicAdd(&wq_bkt[j], h);
    }
    __syncthreads();
#pragma unroll
    for (int i = 0; i < A_ITEMS; ++i) {
        const int idx = base + i * 256 + tid;
        if (idx < NE) {
            const int r = row[idx];
            const int b = r >> 9;
            const int v = col[idx] | (pt[idx] << 19) | ((r & (RB - 1)) << 23);
            const int o   = atomicAdd(&roff[b], 1);
            const int rel = rbase[b] + o;
            if (rel < BCAP) pairs[(size_t)b * BCAP + rel] = v;
        }
    }
}

// --------- stage B: per-bucket sort by row + eig-dot precompute ------------
__global__ void bkt_sort_kernel(const int* __restrict__ wq_bkt,
                                const int* __restrict__ pairs,
                                const float* __restrict__ eigs,
                                int2* __restrict__ rinfo,
                                int2* __restrict__ epacked)
{
    __shared__ int rcnt[RB], lrp[RB], wq2[RB], ssum[256];
    __shared__ int dhist[DBINS], dbase[DBINS];
    __shared__ int perml[RB];
    __shared__ float estage[RB * ED];
    const int tid  = threadIdx.x;
    const int b    = blockIdx.x;
    const int r0   = b * RB;
    const int sbase = b * BCAP;
    int cntb = wq_bkt[b]; if (cntb > BCAP) cntb = BCAP;

    for (int j = tid; j < RB; j += 256) { rcnt[j] = 0; wq2[j] = 0; perml[j] = -1; }
    for (int j = tid; j < DBINS; j += 256) dhist[j] = 0;
    for (int k = tid; k < RB * ED; k += 256) {
        const int g = r0 * ED + k;
        estage[k] = (g < NN * ED) ? eigs[g] : 0.0f;
    }
    __syncthreads();

    for (int i = tid; i < cntb; i += 256)
        atomicAdd(&rcnt[(pairs[sbase + i] >> 23) & (RB - 1)], 1);
    __syncthreads();

    const int a0 = rcnt[2 * tid], a1 = rcnt[2 * tid + 1];
    ssum[tid] = a0 + a1;
    __syncthreads();
    for (int off = 1; off < 256; off <<= 1) {
        int x = (tid >= off) ? ssum[tid - off] : 0;
        __syncthreads();
        ssum[tid] += x;
        __syncthreads();
    }
    const int excl = ssum[tid] - (a0 + a1);
    lrp[2 * tid]     = excl;
    lrp[2 * tid + 1] = excl + a0;
    __syncthreads();

    // ---- within-bucket counting sort by DESCENDING degree -> perml ----
    const int ra   = r0 + 2 * tid;
    const int bin0 = (DBINS - 1) - ((a0 < DBINS - 1) ? a0 : (DBINS - 1));
    const int bin1 = (DBINS - 1) - ((a1 < DBINS - 1) ? a1 : (DBINS - 1));
    if (ra < NN)     atomicAdd(&dhist[bin0], 1);
    if (ra + 1 < NN) atomicAdd(&dhist[bin1], 1);
    __syncthreads();
    ssum[tid] = (tid < DBINS) ? dhist[tid] : 0;
    __syncthreads();
    for (int off = 1; off < DBINS; off <<= 1) {
        int x = (tid >= off) ? ssum[tid - off] : 0;
        __syncthreads();
        ssum[tid] += x;
        __syncthreads();
    }
    if (tid < DBINS) { dbase[tid] = ssum[tid] - dhist[tid]; dhist[tid] = 0; }
    __syncthreads();
    if (ra < NN)     perml[dbase[bin0] + atomicAdd(&dhist[bin0], 1)] = 2 * tid;
    if (ra + 1 < NN) perml[dbase[bin1] + atomicAdd(&dhist[bin1], 1)] = 2 * tid + 1;
    __syncthreads();

    // ---- emit packed rinfo per perm slot ----
    for (int j = tid; j < RB; j += 256) {
        const int rl = perml[j];
        int2 out;
        if (rl >= 0) {
            int dg = rcnt[rl]; if (dg > 0xFFF) dg = 0xFFF;
            out = make_int2(sbase + lrp[rl], (r0 + rl) | (dg << 19));
        } else {
            out = make_int2(0, -1);
        }
        rinfo[r0 + j] = out;
    }

    for (int i = tid; i < cntb; i += 256) {
        const int v  = pairs[sbase + i];
        const int rl = (v >> 23) & (RB - 1);
        const int c  = v & 0x7FFFF;
        const float4* ep = reinterpret_cast<const float4*>(eigs + (size_t)c * ED);
        const float4 q0 = ep[0], q1 = ep[1], q2 = ep[2], q3 = ep[3];
        const float* er = estage + rl * ED;
        float d = q0.x * er[0]  + q0.y * er[1]  + q0.z * er[2]  + q0.w * er[3]
                + q1.x * er[4]  + q1.y * er[5]  + q1.z * er[6]  + q1.w * er[7]
                + q2.x * er[8]  + q2.y * er[9]  + q2.z * er[10] + q2.w * er[11]
                + q3.x * er[12] + q3.y * er[13] + q3.z * er[14] + q3.w * er[15];
        const int o   = atomicAdd(&wq2[rl], 1);
        const int pos = sbase + lrp[rl] + o;
        epacked[pos] = make_int2(v & 0x7FFFFF, __float_as_int(d));
    }
}

// ---------------------------------------------------------------------------
// Fused attention, row-level software pipeline.
// NEW (R10): the io round-trip is eliminated. L0 no longer reads emb0 nor
// writes io; it stores yb2 = LN(out1) plus a per-row (mu, sigma) table so
// out1 is reconstructible (out1 = w*sigma + mu). L1 reconstructs out1 from
// its own yb2 row (already loaded for the dot) and writes the FINAL
// io = (emb0 + out1 + out2)/3 for every valid row (deg==0 included).
// Saves ~153 MB of HBM traffic in L0 at +~0.0005 absmax.
// ---------------------------------------------------------------------------
template <int LAYER>
__global__ __launch_bounds__(256, 4)   // allow up to 128 VGPR
void attn_row_kernel(const bf16* __restrict__ yb,
                     const int2* __restrict__ rinfo,
                     const int2* __restrict__ epacked,
                     const float* __restrict__ lambda0,
                     const float* __restrict__ pemb,
                     const float* __restrict__ user_emb,
                     const float* __restrict__ item_emb,
                     bf16* __restrict__ yb_next,
                     float* __restrict__ lntab,   // [NN*2] {mu, sigma} per row
                     float* __restrict__ io)
{
    __shared__ float e1tab[NP];
    if (threadIdx.x < NP)
        e1tab[threadIdx.x] = __expf(pemb[LAYER * NP + threadIdx.x]);
    __syncthreads();

    const int tid  = (int)threadIdx.x;
    const int gl   = tid >> 3;                    // group in block, 0..31
    const int sub  = tid & 7;
    const int lane = tid & 63;
    const int base = (int)blockIdx.x * (32 * IT);

    const float lam = __expf(lambda0[LAYER]);
    const bf16*  ybs = yb + (size_t)sub * 8;      // lane's dim-slice base
    const int2v* ep2 = reinterpret_cast<const int2v*>(epacked);

    // all IT rinfo up front (coalesced, independent)
    int2 ri[IT];
#pragma unroll
    for (int it = 0; it < IT; ++it) ri[it] = rinfo[base + it * 32 + gl];

    // prime the pipeline: epacked batch of row 0
    int2v myv_n;
    {
        const int2v* mp = ep2 + ri[0].x + sub;
        asm volatile("global_load_dwordx2 %0, %1, off" : "=v"(myv_n) : "v"(mp));
        asm volatile("s_waitcnt vmcnt(0)" : "+v"(myv_n));
    }

#pragma unroll
    for (int it = 0; it < IT; ++it) {
        const int2 ric   = ri[it];
        const bool valid = (ric.y >= 0);
        const int r      = valid ? (ric.y & 0x7FFFF) : 0;
        const int deg    = valid ? ((ric.y >> 19) & 0xFFF) : 0;
        const int start  = ric.x;

        int2v myv = myv_n;
        if (sub >= deg) { myv[0] = 0; myv[1] = 0; }   // mask garbage lanes

        // broadcast the batch's (v, edot) to all lanes of the group
        int   vv[8];
        float ee[8];
#pragma unroll
        for (int kk = 0; kk < 8; ++kk) {
            const int src = (lane & ~7) + kk;
            vv[kk] = __shfl(myv[0], src, 64);
            ee[kk] = __int_as_float(__shfl(myv[1], src, 64));
        }
        const int nb = (deg < 8) ? deg : 8;

        // own-iteration loads hidden under the batch drain:
        // yrf row always; L1 additionally: emb0 row + (mu,sigma) entry
        ushort8v yru;
        float4v em_lo = {0,0,0,0}, em_hi = {0,0,0,0};
        float2v ms = {0,0};
        {
            const bf16* yp = ybs + (size_t)r * HD;
            asm volatile("global_load_dwordx4 %0, %1, off" : "=v"(yru) : "v"(yp));
            if (LAYER == 1) {
                const float* ep = ((r < NU) ? user_emb + (size_t)r * HD
                                            : item_emb + (size_t)(r - NU) * HD) + sub * 8;
                asm volatile("global_load_dwordx4 %0, %1, off" : "=v"(em_lo) : "v"(ep));
                asm volatile("global_load_dwordx4 %0, %1, off" : "=v"(em_hi) : "v"(ep + 4));
                const float* tp = lntab + 2 * (size_t)r;
                asm volatile("global_load_dwordx2 %0, %1, off" : "=v"(ms) : "v"(tp));
            }
        }

        // batch gather cluster (8 rows; padded lanes read row 0, harmless)
        const bf16* p0 = ybs + (size_t)(vv[0] & 0x7FFFF) * HD;
        const bf16* p1 = ybs + (size_t)(vv[1] & 0x7FFFF) * HD;
        const bf16* p2 = ybs + (size_t)(vv[2] & 0x7FFFF) * HD;
        const bf16* p3 = ybs + (size_t)(vv[3] & 0x7FFFF) * HD;
        const bf16* p4 = ybs + (size_t)(vv[4] & 0x7FFFF) * HD;
        const bf16* p5 = ybs + (size_t)(vv[5] & 0x7FFFF) * HD;
        const bf16* p6 = ybs + (size_t)(vv[6] & 0x7FFFF) * HD;
        const bf16* p7 = ybs + (size_t)(vv[7] & 0x7FFFF) * HD;
        ushort8v u0, u1, u2, u3, u4, u5, u6, u7;
        asm volatile("global_load_dwordx4 %0, %1, off" : "=v"(u0) : "v"(p0));
        asm volatile("global_load_dwordx4 %0, %1, off" : "=v"(u1) : "v"(p1));
        asm volatile("global_load_dwordx4 %0, %1, off" : "=v"(u2) : "v"(p2));
        asm volatile("global_load_dwordx4 %0, %1, off" : "=v"(u3) : "v"(p3));
        asm volatile("global_load_dwordx4 %0, %1, off" : "=v"(u4) : "v"(p4));
        asm volatile("global_load_dwordx4 %0, %1, off" : "=v"(u5) : "v"(p5));
        asm volatile("global_load_dwordx4 %0, %1, off" : "=v"(u6) : "v"(p6));
        asm volatile("global_load_dwordx4 %0, %1, off" : "=v"(u7) : "v"(p7));

        // cross-iteration prefetch: next row's epacked batch (needs ri only)
        if (it + 1 < IT) {
            const int2v* mp = ep2 + ri[it + 1].x + sub;
            asm volatile("global_load_dwordx2 %0, %1, off" : "=v"(myv_n) : "v"(mp));
        }

        // single drain per row
        asm volatile("s_waitcnt vmcnt(0)"
                     : "+v"(u0), "+v"(u1), "+v"(u2), "+v"(u3),
                       "+v"(u4), "+v"(u5), "+v"(u6), "+v"(u7),
                       "+v"(yru), "+v"(em_lo), "+v"(em_hi), "+v"(ms), "+v"(myv_n));

        float yrf[8];
#pragma unroll
        for (int j = 0; j < 8; ++j) yrf[j] = bf2f(yru[j]);

        float U0[8], U1[8];
#pragma unroll
        for (int j = 0; j < 8; ++j) { U0[j] = 0.0f; U1[j] = 0.0f; }
        float d0 = 0.0f, d1 = 0.0f;

        auto consume = [&](const ushort8v& uc, int vk, float ek) {
            float yc[8];
            float sdot = 0.0f;
#pragma unroll
            for (int j = 0; j < 8; ++j) { yc[j] = bf2f(uc[j]); sdot += yrf[j] * yc[j]; }
            sdot += __shfl_xor(sdot, 1, 64);
            sdot += __shfl_xor(sdot, 2, 64);
            sdot += __shfl_xor(sdot, 4, 64);
            const float e0 = __expf(sdot * 0.125f + lam * ek);
            const float e1 = e1tab[(vk >> 19) & 15];
            d0 += e0; d1 += e1;
#pragma unroll
            for (int j = 0; j < 8; ++j) {
                U0[j] += e0 * yc[j];
                U1[j] += e1 * yc[j];
            }
        };
        if (nb > 0) consume(u0, vv[0], ee[0]);
        if (nb > 1) consume(u1, vv[1], ee[1]);
        if (nb > 2) consume(u2, vv[2], ee[2]);
        if (nb > 3) consume(u3, vv[3], ee[3]);
        if (nb > 4) consume(u4, vv[4], ee[4]);
        if (nb > 5) consume(u5, vv[5], ee[5]);
        if (nb > 6) consume(u6, vv[6], ee[6]);
        if (nb > 7) consume(u7, vv[7], ee[7]);

        // rare multi-batch tail (deg > 8, ~4% of rows; plain C path)
        for (int k0 = 8; k0 < deg; k0 += 8) {
            int2 mv = ((k0 + sub) < deg) ? epacked[start + k0 + sub]
                                         : make_int2(0, 0);
            int   vv2[8];
            float ee2[8];
#pragma unroll
            for (int kk = 0; kk < 8; ++kk) {
                const int src = (lane & ~7) + kk;
                vv2[kk] = __shfl(mv.x, src, 64);
                ee2[kk] = __int_as_float(__shfl(mv.y, src, 64));
            }
            const int nb2 = ((deg - k0) < 8) ? (deg - k0) : 8;
#pragma unroll
            for (int kk = 0; kk < 8; ++kk) {
                if (kk < nb2) {
                    ushort8v uc = *reinterpret_cast<const ushort8v*>(
                        ybs + (size_t)(vv2[kk] & 0x7FFFF) * HD);
                    consume(uc, vv2[kk], ee2[kk]);
                }
            }
        }

        const float i0 = deg ? 0.5f / d0 : 0.0f;
        const float i1 = deg ? 0.5f / d1 : 0.0f;
        float acc[8];
#pragma unroll
        for (int j = 0; j < 8; ++j) acc[j] = i0 * U0[j] + i1 * U1[j];

        if (LAYER == 0) {
            if (valid) {   // LN(out1) -> yb_next; (mu,sigma) -> lntab. No io.
                float sm = 0.0f, sq = 0.0f;
#pragma unroll
                for (int j = 0; j < 8; ++j) { sm += acc[j]; sq += acc[j] * acc[j]; }
                sm += __shfl_xor(sm, 1, 64); sq += __shfl_xor(sq, 1, 64);
                sm += __shfl_xor(sm, 2, 64); sq += __shfl_xor(sq, 2, 64);
                sm += __shfl_xor(sm, 4, 64); sq += __shfl_xor(sq, 4, 64);
                const float mu  = sm * (1.0f / 64.0f);
                const float var = sq * (1.0f / 64.0f) - mu * mu;
                const float inv = rsqrtf(var + 1e-5f);
                ushort8v w;
#pragma unroll
                for (int j = 0; j < 8; ++j) w[j] = f2b((acc[j] - mu) * inv);
                *reinterpret_cast<ushort8v*>(yb_next + (size_t)r * HD + sub * 8) = w;
                if (sub == 0) {
                    float2v t; t[0] = mu; t[1] = sqrtf(var + 1e-5f);
                    *reinterpret_cast<float2v*>(lntab + 2 * (size_t)r) = t;
                }
            }
        } else {
            if (valid) {   // io = (emb0 + out1 + out2)/3; out1 = w*sigma + mu
                float* iorow = io + (size_t)r * HD + sub * 8;
                const float third = 1.0f / 3.0f;
                float4v o0, o1;
#pragma unroll
                for (int j = 0; j < 4; ++j) {
                    const float out1 = yrf[j] * ms[1] + ms[0];
                    o0[j] = (em_lo[j] + out1 + acc[j]) * third;
                }
#pragma unroll
                for (int j = 0; j < 4; ++j) {
                    const float out1 = yrf[j + 4] * ms[1] + ms[0];
                    o1[j] = (em_hi[j] + out1 + acc[j + 4]) * third;
                }
                *reinterpret_cast<float4v*>(iorow)     = o0;
                *reinterpret_cast<float4v*>(iorow + 4) = o1;
            }
        }
    }
}

extern "C" void kernel_launch(void* const* d_in, const int* in_sizes, int n_in,
                              void* d_out, int out_size, void* d_ws, size_t ws_size,
                              hipStream_t stream)
{
    const float* user_emb = (const float*)d_in[0];
    const float* item_emb = (const float*)d_in[1];
    const float* eigs     = (const float*)d_in[2];
    const float* lambda0  = (const float*)d_in[3];
    const float* pemb     = (const float*)d_in[4];
    const int*   indices  = (const int*)d_in[5];
    const int*   ptype    = (const int*)d_in[6];
    const int*   row = indices;
    const int*   col = indices + NE;

    float* io = (float*)d_out;                        // NN*HD fp32 final output
    char*  ws = (char*)d_ws;
    bf16*  yb      = (bf16*)ws;                       // 38.4 MB
    bf16*  yb2     = yb + (size_t)NN * HD;            // 38.4 MB
    int*   pairs   = (int*)(yb2 + (size_t)NN * HD);   // NBKT*BCAP (5.7 MB)
    int2*  epacked = (int2*)(pairs + (size_t)NBKT * BCAP);  // NBKT*BCAP int2 (11.4 MB)
    int2*  rinfo   = epacked + (size_t)NBKT * BCAP;   // NR8 int2 (2.4 MB)
    float* lntab   = (float*)(rinfo + NR8);           // NN*2 fp32 (2.4 MB)
    int*   wq_bkt  = (int*)(lntab + 2 * (size_t)NN);  // NBKT
    // total ws ~ 98.7 MB

    const dim3 blk(256);
    const int gridAttn = NR8 / (32 * IT);             // 2344 blocks, 4 rows/group

    // ---- LayerNorm (independent of CSR build) ----
    ln_kernel<<<(NN * 8 + 255) / 256, blk, 0, stream>>>(user_emb, item_emb, yb);

    // ---- CSR build: single-pass fixed-stride binning + sort ----
    hipMemsetAsync(wq_bkt, 0, NBKT * sizeof(int), stream);
    bkt_scatter_kernel<<<A_BLOCKS, blk, 0, stream>>>(row, col, ptype, wq_bkt, pairs);
    bkt_sort_kernel<<<NBKT, blk, 0, stream>>>(wq_bkt, pairs, eigs, rinfo, epacked);

    // ---- layer 0: out1 -> LN -> yb2 + (mu,sigma) table (no emb0/io) ----
    attn_row_kernel<0><<<gridAttn, blk, 0, stream>>>(yb, rinfo, epacked,
                                                     lambda0, pemb, user_emb,
                                                     item_emb, yb2, lntab, io);
    // ---- layer 1: io = (emb0 + out1 + out2)/3, final output ----
    attn_row_kernel<1><<<gridAttn, blk, 0, stream>>>(yb2, rinfo, epacked,
                                                     lambda0, pemb, user_emb,
                                                     item_emb, nullptr, lntab, io);
}

// Round 13
// 355.348 us; speedup vs baseline: 1.1675x; 1.0595x over previous
//
#include <hip/hip_runtime.h>
#include <hip/hip_bf16.h>

#define HD 64
#define ED 16
#define NU 100000
#define NI 200000
#define NN 300000
#define NE 1250000
#define NP 14

#define RB 512                         // rows per bucket (9 bits)
#define NBKT ((NN + RB - 1) / RB)      // 586 buckets
#define NR8 (NBKT * RB)                // 300032 perm slots (tail invalid)
#define BCAP 2432                      // fixed bucket capacity (mean 2133 + 6.5 sigma)
#define A_ITEMS 8
#define A_CHUNK (256 * A_ITEMS)        // 2048 edges per binning block
#define A_BLOCKS ((NE + A_CHUNK - 1) / A_CHUNK)   // 611
#define DBINS 64                       // degree-sort bins (bin clamped at 63)
#define IT 4                           // rows per group (pipelined)

typedef __hip_bfloat16 bf16;
typedef unsigned short ushort8v __attribute__((ext_vector_type(8)));
typedef float  float4v __attribute__((ext_vector_type(4)));
typedef float  float2v __attribute__((ext_vector_type(2)));
typedef int    int2v   __attribute__((ext_vector_type(2)));

__device__ __forceinline__ float bf2f(unsigned short u) {
    union { unsigned int i; float f; } c; c.i = ((unsigned int)u) << 16; return c.f;
}
__device__ __forceinline__ unsigned short f2b(float x) {
    bf16 h = __float2bfloat16(x);
    unsigned short u; __builtin_memcpy(&u, &h, 2); return u;
}

// ---------------------------------------------------------------------------
// LayerNorm of input embeddings, 8-lane group per row (lane = 8 dims).
// ---------------------------------------------------------------------------
__global__ void ln_kernel(const float* __restrict__ user_emb,
                          const float* __restrict__ item_emb,
                          bf16* __restrict__ yb)
{
    const int tid = blockIdx.x * blockDim.x + threadIdx.x;
    const int r   = tid >> 3;
    const int sub = tid & 7;
    if (r >= NN) return;
    const float* src = (r < NU) ? user_emb + (size_t)r * HD
                                : item_emb + (size_t)(r - NU) * HD;
    const float4 lo = *reinterpret_cast<const float4*>(src + sub * 8);
    const float4 hi = *reinterpret_cast<const float4*>(src + sub * 8 + 4);
    float x[8] = {lo.x, lo.y, lo.z, lo.w, hi.x, hi.y, hi.z, hi.w};

    float sm = 0.0f, sq = 0.0f;
#pragma unroll
    for (int j = 0; j < 8; ++j) { sm += x[j]; sq += x[j] * x[j]; }
    sm += __shfl_xor(sm, 1, 64); sq += __shfl_xor(sq, 1, 64);
    sm += __shfl_xor(sm, 2, 64); sq += __shfl_xor(sq, 2, 64);
    sm += __shfl_xor(sm, 4, 64); sq += __shfl_xor(sq, 4, 64);
    const float mu  = sm * (1.0f / 64.0f);
    const float var = sq * (1.0f / 64.0f) - mu * mu;
    const float inv = rsqrtf(var + 1e-5f);

    ushort8v w;
#pragma unroll
    for (int j = 0; j < 8; ++j) w[j] = f2b((x[j] - mu) * inv);
    *reinterpret_cast<ushort8v*>(yb + (size_t)r * HD + sub * 8) = w;
}

// --------- single-pass binning: fixed-stride buckets (no count/scan) -------
__global__ void bkt_scatter_kernel(const int* __restrict__ row,
                                   const int* __restrict__ col,
                                   const int* __restrict__ pt,
                                   int* __restrict__ wq_bkt,
                                   int* __restrict__ pairs)
{
    __shared__ int hist[NBKT];
    __shared__ int rbase[NBKT];
    __shared__ int roff[NBKT];
    const int tid = threadIdx.x;
    for (int j = tid; j < NBKT; j += 256) { hist[j] = 0; roff[j] = 0; }
    __syncthreads();

    const int base = blockIdx.x * A_CHUNK;
#pragma unroll
    for (int i = 0; i < A_ITEMS; ++i) {
        const int idx = base + i * 256 + tid;
        if (idx < NE) atomicAdd(&hist[row[idx] >> 9], 1);
    }
    __syncthreads();
    for (int j = tid; j < NBKT; j += 256) {
        const int h = hist[j];
        if (h) rbase[j] = atomicAdd(&wq_bkt[j], h);
    }
    __syncthreads();
#pragma unroll
    for (int i = 0; i < A_ITEMS; ++i) {
        const int idx = base + i * 256 + tid;
        if (idx < NE) {
            const int r = row[idx];
            const int b = r >> 9;
            const int v = col[idx] | (pt[idx] << 19) | ((r & (RB - 1)) << 23);
            const int o   = atomicAdd(&roff[b], 1);
            const int rel = rbase[b] + o;
            if (rel < BCAP) pairs[(size_t)b * BCAP + rel] = v;
        }
    }
}

// --------- stage B: per-bucket sort by row + eig-dot precompute ------------
// 512 threads (8 waves: direct 512-elem scan + latency hiding in eig pass).
// rinfo emitted through a BALANCE REMAP: sorted octet rank R -> position
// N = ((R&3)<<4)|(R>>2) (bijection on 64 octets). Round-robins heavy/light
// octets across the bucket's 4 attn blocks and their waves, fixing the
// block-runtime skew the desc-sort created (R10: avg occupancy 30% from the
// light-blocks-finish-early tail). Wave-iteration slots stay sorted-adjacent
// (deg-uniform within each 8-lane group's octet).
__global__ __launch_bounds__(512)
void bkt_sort_kernel(const int* __restrict__ wq_bkt,
                     const int* __restrict__ pairs,
                     const float* __restrict__ eigs,
                     int2* __restrict__ rinfo,
                     int2* __restrict__ epacked)
{
    __shared__ int rcnt[RB], lrp[RB], wq2[RB], ssum[RB];
    __shared__ int dhist[DBINS], dbase[DBINS];
    __shared__ int perml[RB];
    __shared__ float estage[RB * ED];
    const int tid  = threadIdx.x;          // 0..511
    const int b    = blockIdx.x;
    const int r0   = b * RB;
    const int sbase = b * BCAP;
    int cntb = wq_bkt[b]; if (cntb > BCAP) cntb = BCAP;

    rcnt[tid] = 0; wq2[tid] = 0; perml[tid] = -1;
    if (tid < DBINS) dhist[tid] = 0;
    for (int k = tid; k < RB * ED; k += 512) {
        const int g = r0 * ED + k;
        estage[k] = (g < NN * ED) ? eigs[g] : 0.0f;
    }
    __syncthreads();

    for (int i = tid; i < cntb; i += 512)
        atomicAdd(&rcnt[(pairs[sbase + i] >> 23) & (RB - 1)], 1);
    __syncthreads();

    // exclusive scan of per-row counts (512 elements, Hillis-Steele)
    const int myc = rcnt[tid];
    ssum[tid] = myc;
    __syncthreads();
    for (int off = 1; off < RB; off <<= 1) {
        int x = (tid >= off) ? ssum[tid - off] : 0;
        __syncthreads();
        ssum[tid] += x;
        __syncthreads();
    }
    lrp[tid] = ssum[tid] - myc;
    __syncthreads();

    // ---- counting sort by DESCENDING degree -> perml ----
    const int ra  = r0 + tid;
    const int bin = (DBINS - 1) - ((myc < DBINS - 1) ? myc : (DBINS - 1));
    if (ra < NN) atomicAdd(&dhist[bin], 1);
    __syncthreads();
    if (tid < DBINS) ssum[tid] = dhist[tid];
    __syncthreads();
    for (int off = 1; off < DBINS; off <<= 1) {
        int x = (tid < DBINS && tid >= off) ? ssum[tid - off] : 0;
        __syncthreads();
        if (tid < DBINS) ssum[tid] += x;
        __syncthreads();
    }
    if (tid < DBINS) { dbase[tid] = ssum[tid] - dhist[tid]; dhist[tid] = 0; }
    __syncthreads();
    if (ra < NN) perml[dbase[bin] + atomicAdd(&dhist[bin], 1)] = tid;
    __syncthreads();

    // ---- emit packed rinfo through the balance remap ----
    {
        const int j  = tid;                 // sorted rank
        const int R  = j >> 3, o = j & 7;   // octet rank, in-octet pos
        const int N  = ((R & 3) << 4) | (R >> 2);
        const int pos = (N << 3) | o;
        const int rl = perml[j];
        int2 out;
        if (rl >= 0) {
            int dg = rcnt[rl]; if (dg > 0xFFF) dg = 0xFFF;
            out = make_int2(sbase + lrp[rl], (r0 + rl) | (dg << 19));
        } else {
            out = make_int2(0, -1);
        }
        rinfo[r0 + pos] = out;
    }

    for (int i = tid; i < cntb; i += 512) {
        const int v  = pairs[sbase + i];
        const int rl = (v >> 23) & (RB - 1);
        const int c  = v & 0x7FFFF;
        const float4* ep = reinterpret_cast<const float4*>(eigs + (size_t)c * ED);
        const float4 q0 = ep[0], q1 = ep[1], q2 = ep[2], q3 = ep[3];
        const float* er = estage + rl * ED;
        float d = q0.x * er[0]  + q0.y * er[1]  + q0.z * er[2]  + q0.w * er[3]
                + q1.x * er[4]  + q1.y * er[5]  + q1.z * er[6]  + q1.w * er[7]
                + q2.x * er[8]  + q2.y * er[9]  + q2.z * er[10] + q2.w * er[11]
                + q3.x * er[12] + q3.y * er[13] + q3.z * er[14] + q3.w * er[15];
        const int o   = atomicAdd(&wq2[rl], 1);
        const int pos = sbase + lrp[rl] + o;
        epacked[pos] = make_int2(v & 0x7FFFFF, __float_as_int(d));
    }
}

// ---------------------------------------------------------------------------
// Fused attention, row-level software pipeline (kernel unchanged from R10;
// slot->row mapping balanced by the producer-side remap).
// L0: yb2 = LN(out1) + (mu,sigma) table. L1: io = (emb0 + out1 + out2)/3.
// ---------------------------------------------------------------------------
template <int LAYER>
__global__ __launch_bounds__(256, 4)
void attn_row_kernel(const bf16* __restrict__ yb,
                     const int2* __restrict__ rinfo,
                     const int2* __restrict__ epacked,
                     const float* __restrict__ lambda0,
                     const float* __restrict__ pemb,
                     const float* __restrict__ user_emb,
                     const float* __restrict__ item_emb,
                     bf16* __restrict__ yb_next,
                     float* __restrict__ lntab,   // [NN*2] {mu, sigma} per row
                     float* __restrict__ io)
{
    __shared__ float e1tab[NP];
    if (threadIdx.x < NP)
        e1tab[threadIdx.x] = __expf(pemb[LAYER * NP + threadIdx.x]);
    __syncthreads();

    const int tid  = (int)threadIdx.x;
    const int gl   = tid >> 3;                    // group in block, 0..31
    const int sub  = tid & 7;
    const int lane = tid & 63;
    const int base = (int)blockIdx.x * (32 * IT);

    const float lam = __expf(lambda0[LAYER]);
    const bf16*  ybs = yb + (size_t)sub * 8;      // lane's dim-slice base
    const int2v* ep2 = reinterpret_cast<const int2v*>(epacked);

    // all IT rinfo up front (coalesced, independent)
    int2 ri[IT];
#pragma unroll
    for (int it = 0; it < IT; ++it) ri[it] = rinfo[base + it * 32 + gl];

    // prime the pipeline: epacked batch of row 0
    int2v myv_n;
    {
        const int2v* mp = ep2 + ri[0].x + sub;
        asm volatile("global_load_dwordx2 %0, %1, off" : "=v"(myv_n) : "v"(mp));
        asm volatile("s_waitcnt vmcnt(0)" : "+v"(myv_n));
    }

#pragma unroll
    for (int it = 0; it < IT; ++it) {
        const int2 ric   = ri[it];
        const bool valid = (ric.y >= 0);
        const int r      = valid ? (ric.y & 0x7FFFF) : 0;
        const int deg    = valid ? ((ric.y >> 19) & 0xFFF) : 0;
        const int start  = ric.x;

        int2v myv = myv_n;
        if (sub >= deg) { myv[0] = 0; myv[1] = 0; }   // mask garbage lanes

        // broadcast the batch's (v, edot) to all lanes of the group
        int   vv[8];
        float ee[8];
#pragma unroll
        for (int kk = 0; kk < 8; ++kk) {
            const int src = (lane & ~7) + kk;
            vv[kk] = __shfl(myv[0], src, 64);
            ee[kk] = __int_as_float(__shfl(myv[1], src, 64));
        }
        const int nb = (deg < 8) ? deg : 8;

        // own-iteration loads hidden under the batch drain:
        // yrf row always; L1 additionally: emb0 row + (mu,sigma) entry
        ushort8v yru;
        float4v em_lo = {0,0,0,0}, em_hi = {0,0,0,0};
        float2v ms = {0,0};
        {
            const bf16* yp = ybs + (size_t)r * HD;
            asm volatile("global_load_dwordx4 %0, %1, off" : "=v"(yru) : "v"(yp));
            if (LAYER == 1) {
                const float* ep = ((r < NU) ? user_emb + (size_t)r * HD
                                            : item_emb + (size_t)(r - NU) * HD) + sub * 8;
                asm volatile("global_load_dwordx4 %0, %1, off" : "=v"(em_lo) : "v"(ep));
                asm volatile("global_load_dwordx4 %0, %1, off" : "=v"(em_hi) : "v"(ep + 4));
                const float* tp = lntab + 2 * (size_t)r;
                asm volatile("global_load_dwordx2 %0, %1, off" : "=v"(ms) : "v"(tp));
            }
        }

        // batch gather cluster (8 rows; padded lanes read row 0, harmless)
        const bf16* p0 = ybs + (size_t)(vv[0] & 0x7FFFF) * HD;
        const bf16* p1 = ybs + (size_t)(vv[1] & 0x7FFFF) * HD;
        const bf16* p2 = ybs + (size_t)(vv[2] & 0x7FFFF) * HD;
        const bf16* p3 = ybs + (size_t)(vv[3] & 0x7FFFF) * HD;
        const bf16* p4 = ybs + (size_t)(vv[4] & 0x7FFFF) * HD;
        const bf16* p5 = ybs + (size_t)(vv[5] & 0x7FFFF) * HD;
        const bf16* p6 = ybs + (size_t)(vv[6] & 0x7FFFF) * HD;
        const bf16* p7 = ybs + (size_t)(vv[7] & 0x7FFFF) * HD;
        ushort8v u0, u1, u2, u3, u4, u5, u6, u7;
        asm volatile("global_load_dwordx4 %0, %1, off" : "=v"(u0) : "v"(p0));
        asm volatile("global_load_dwordx4 %0, %1, off" : "=v"(u1) : "v"(p1));
        asm volatile("global_load_dwordx4 %0, %1, off" : "=v"(u2) : "v"(p2));
        asm volatile("global_load_dwordx4 %0, %1, off" : "=v"(u3) : "v"(p3));
        asm volatile("global_load_dwordx4 %0, %1, off" : "=v"(u4) : "v"(p4));
        asm volatile("global_load_dwordx4 %0, %1, off" : "=v"(u5) : "v"(p5));
        asm volatile("global_load_dwordx4 %0, %1, off" : "=v"(u6) : "v"(p6));
        asm volatile("global_load_dwordx4 %0, %1, off" : "=v"(u7) : "v"(p7));

        // cross-iteration prefetch: next row's epacked batch (needs ri only)
        if (it + 1 < IT) {
            const int2v* mp = ep2 + ri[it + 1].x + sub;
            asm volatile("global_load_dwordx2 %0, %1, off" : "=v"(myv_n) : "v"(mp));
        }

        // single drain per row
        asm volatile("s_waitcnt vmcnt(0)"
                     : "+v"(u0), "+v"(u1), "+v"(u2), "+v"(u3),
                       "+v"(u4), "+v"(u5), "+v"(u6), "+v"(u7),
                       "+v"(yru), "+v"(em_lo), "+v"(em_hi), "+v"(ms), "+v"(myv_n));

        float yrf[8];
#pragma unroll
        for (int j = 0; j < 8; ++j) yrf[j] = bf2f(yru[j]);

        float U0[8], U1[8];
#pragma unroll
        for (int j = 0; j < 8; ++j) { U0[j] = 0.0f; U1[j] = 0.0f; }
        float d0 = 0.0f, d1 = 0.0f;

        auto consume = [&](const ushort8v& uc, int vk, float ek) {
            float yc[8];
            float sdot = 0.0f;
#pragma unroll
            for (int j = 0; j < 8; ++j) { yc[j] = bf2f(uc[j]); sdot += yrf[j] * yc[j]; }
            sdot += __shfl_xor(sdot, 1, 64);
            sdot += __shfl_xor(sdot, 2, 64);
            sdot += __shfl_xor(sdot, 4, 64);
            const float e0 = __expf(sdot * 0.125f + lam * ek);
            const float e1 = e1tab[(vk >> 19) & 15];
            d0 += e0; d1 += e1;
#pragma unroll
            for (int j = 0; j < 8; ++j) {
                U0[j] += e0 * yc[j];
                U1[j] += e1 * yc[j];
            }
        };
        if (nb > 0) consume(u0, vv[0], ee[0]);
        if (nb > 1) consume(u1, vv[1], ee[1]);
        if (nb > 2) consume(u2, vv[2], ee[2]);
        if (nb > 3) consume(u3, vv[3], ee[3]);
        if (nb > 4) consume(u4, vv[4], ee[4]);
        if (nb > 5) consume(u5, vv[5], ee[5]);
        if (nb > 6) consume(u6, vv[6], ee[6]);
        if (nb > 7) consume(u7, vv[7], ee[7]);

        // rare multi-batch tail (deg > 8, ~4% of rows; plain C path)
        for (int k0 = 8; k0 < deg; k0 += 8) {
            int2 mv = ((k0 + sub) < deg) ? epacked[start + k0 + sub]
                                         : make_int2(0, 0);
            int   vv2[8];
            float ee2[8];
#pragma unroll
            for (int kk = 0; kk < 8; ++kk) {
                const int src = (lane & ~7) + kk;
                vv2[kk] = __shfl(mv.x, src, 64);
                ee2[kk] = __int_as_float(__shfl(mv.y, src, 64));
            }
            const int nb2 = ((deg - k0) < 8) ? (deg - k0) : 8;
#pragma unroll
            for (int kk = 0; kk < 8; ++kk) {
                if (kk < nb2) {
                    ushort8v uc = *reinterpret_cast<const ushort8v*>(
                        ybs + (size_t)(vv2[kk] & 0x7FFFF) * HD);
                    consume(uc, vv2[kk], ee2[kk]);
                }
            }
        }

        const float i0 = deg ? 0.5f / d0 : 0.0f;
        const float i1 = deg ? 0.5f / d1 : 0.0f;
        float acc[8];
#pragma unroll
        for (int j = 0; j < 8; ++j) acc[j] = i0 * U0[j] + i1 * U1[j];

        if (LAYER == 0) {
            if (valid) {   // LN(out1) -> yb_next; (mu,sigma) -> lntab. No io.
                float sm = 0.0f, sq = 0.0f;
#pragma unroll
                for (int j = 0; j < 8; ++j) { sm += acc[j]; sq += acc[j] * acc[j]; }
                sm += __shfl_xor(sm, 1, 64); sq += __shfl_xor(sq, 1, 64);
                sm += __shfl_xor(sm, 2, 64); sq += __shfl_xor(sq, 2, 64);
                sm += __shfl_xor(sm, 4, 64); sq += __shfl_xor(sq, 4, 64);
                const float mu  = sm * (1.0f / 64.0f);
                const float var = sq * (1.0f / 64.0f) - mu * mu;
                const float inv = rsqrtf(var + 1e-5f);
                ushort8v w;
#pragma unroll
                for (int j = 0; j < 8; ++j) w[j] = f2b((acc[j] - mu) * inv);
                *reinterpret_cast<ushort8v*>(yb_next + (size_t)r * HD + sub * 8) = w;
                if (sub == 0) {
                    float2v t; t[0] = mu; t[1] = sqrtf(var + 1e-5f);
                    *reinterpret_cast<float2v*>(lntab + 2 * (size_t)r) = t;
                }
            }
        } else {
            if (valid) {   // io = (emb0 + out1 + out2)/3; out1 = w*sigma + mu
                float* iorow = io + (size_t)r * HD + sub * 8;
                const float third = 1.0f / 3.0f;
                float4v o0, o1;
#pragma unroll
                for (int j = 0; j < 4; ++j) {
                    const float out1 = yrf[j] * ms[1] + ms[0];
                    o0[j] = (em_lo[j] + out1 + acc[j]) * third;
                }
#pragma unroll
                for (int j = 0; j < 4; ++j) {
                    const float out1 = yrf[j + 4] * ms[1] + ms[0];
                    o1[j] = (em_hi[j] + out1 + acc[j + 4]) * third;
                }
                *reinterpret_cast<float4v*>(iorow)     = o0;
                *reinterpret_cast<float4v*>(iorow + 4) = o1;
            }
        }
    }
}

extern "C" void kernel_launch(void* const* d_in, const int* in_sizes, int n_in,
                              void* d_out, int out_size, void* d_ws, size_t ws_size,
                              hipStream_t stream)
{
    const float* user_emb = (const float*)d_in[0];
    const float* item_emb = (const float*)d_in[1];
    const float* eigs     = (const float*)d_in[2];
    const float* lambda0  = (const float*)d_in[3];
    const float* pemb     = (const float*)d_in[4];
    const int*   indices  = (const int*)d_in[5];
    const int*   ptype    = (const int*)d_in[6];
    const int*   row = indices;
    const int*   col = indices + NE;

    float* io = (float*)d_out;                        // NN*HD fp32 final output
    char*  ws = (char*)d_ws;
    bf16*  yb      = (bf16*)ws;                       // 38.4 MB
    bf16*  yb2     = yb + (size_t)NN * HD;            // 38.4 MB
    int*   pairs   = (int*)(yb2 + (size_t)NN * HD);   // NBKT*BCAP (5.7 MB)
    int2*  epacked = (int2*)(pairs + (size_t)NBKT * BCAP);  // NBKT*BCAP int2 (11.4 MB)
    int2*  rinfo   = epacked + (size_t)NBKT * BCAP;   // NR8 int2 (2.4 MB)
    float* lntab   = (float*)(rinfo + NR8);           // NN*2 fp32 (2.4 MB)
    int*   wq_bkt  = (int*)(lntab + 2 * (size_t)NN);  // NBKT
    // total ws ~ 98.7 MB

    const dim3 blk(256);
    const int gridAttn = NR8 / (32 * IT);             // 2344 blocks, 4 rows/group

    // ---- LayerNorm (independent of CSR build) ----
    ln_kernel<<<(NN * 8 + 255) / 256, blk, 0, stream>>>(user_emb, item_emb, yb);

    // ---- CSR build: single-pass fixed-stride binning + balanced sort ----
    hipMemsetAsync(wq_bkt, 0, NBKT * sizeof(int), stream);
    bkt_scatter_kernel<<<A_BLOCKS, blk, 0, stream>>>(row, col, ptype, wq_bkt, pairs);
    bkt_sort_kernel<<<NBKT, dim3(512), 0, stream>>>(wq_bkt, pairs, eigs, rinfo, epacked);

    // ---- layer 0: out1 -> LN -> yb2 + (mu,sigma) table (no emb0/io) ----
    attn_row_kernel<0><<<gridAttn, blk, 0, stream>>>(yb, rinfo, epacked,
                                                     lambda0, pemb, user_emb,
                                                     item_emb, yb2, lntab, io);
    // ---- layer 1: io = (emb0 + out1 + out2)/3, final output ----
    attn_row_kernel<1><<<gridAttn, blk, 0, stream>>>(yb2, rinfo, epacked,
                                                     lambda0, pemb, user_emb,
                                                     item_emb, nullptr, lntab, io);
}